// Round 8
// baseline (342.833 us; speedup 1.0000x reference)
//
#include <hip/hip_runtime.h>
#include <hip/hip_bf16.h>

#define DI     1536
#define DM     768
#define E2     3072
#define NST    16
#define LSEQ   2048
#define NB     2
#define NLB    4096
#define SSMW   80
#define DTRANK 48
#define NC     32     // scan chunks
#define CP     64     // chunk length = LSEQ/NC
#define LOG2E  1.44269504f

typedef unsigned short u16;
typedef unsigned int   u32;
typedef __attribute__((ext_vector_type(8))) __bf16 bf16x8;
typedef __attribute__((ext_vector_type(4))) float  f32x4;

__device__ __forceinline__ float b2f(u16 u) {
  union { u32 i; float f; } v; v.i = ((u32)u) << 16; return v.f;
}
__device__ __forceinline__ u16 f2b(float f) {
  union { float f; u32 i; } v; v.f = f;
  u32 r = v.i + 0x7FFFu + ((v.i >> 16) & 1u);
  return (u16)(r >> 16);
}
__device__ __forceinline__ void gld16(const u16* g, u16* l) {
  __builtin_amdgcn_global_load_lds(
      (const __attribute__((address_space(1))) void*)g,
      (__attribute__((address_space(3))) void*)l, 16, 0, 0);
}
__device__ __forceinline__ float silu_f(float x) {
  return x / (1.f + __expf(-x));
}

#define B2F_LO(w) __uint_as_float(((u32)(w)) << 16)
#define B2F_HI(w) __uint_as_float(((u32)(w)) & 0xFFFF0000u)

// full 16-lane-row sum via DPP rotations; every lane gets the total. Pure VALU.
#define ROWSUM16(p)                                                                               \
  asm("v_add_f32 %0, %1, %2 row_ror:8 row_mask:0xf bank_mask:0xf" : "=v"(p) : "v"(p), "v"(p));    \
  asm("v_add_f32 %0, %1, %2 row_ror:4 row_mask:0xf bank_mask:0xf" : "=v"(p) : "v"(p), "v"(p));    \
  asm("v_add_f32 %0, %1, %2 row_ror:2 row_mask:0xf bank_mask:0xf" : "=v"(p) : "v"(p), "v"(p));    \
  asm("v_add_f32 %0, %1, %2 row_ror:1 row_mask:0xf bank_mask:0xf" : "=v"(p) : "v"(p), "v"(p));

// ---------------- fused cast f32 -> bf16 for all 4 weight/input buffers ----------------
__global__ __launch_bounds__(256) void castall(const float* __restrict__ x_in,
                                               const float* __restrict__ w_in,
                                               const float* __restrict__ w_out,
                                               const float* __restrict__ w_x,
                                               u16* __restrict__ in_b,
                                               u16* __restrict__ win_b,
                                               u16* __restrict__ wout_b,
                                               u16* __restrict__ wx_b) {
  int i = (blockIdx.x * 256 + threadIdx.x) * 4;
  const int n1 = NLB * DM, n2 = n1 + E2 * DM, n3 = n2 + DM * DI, n4 = n3 + SSMW * DI;
  const float* src; u16* dst; int off;
  if (i < n1)      { src = x_in;  dst = in_b;   off = i; }
  else if (i < n2) { src = w_in;  dst = win_b;  off = i - n1; }
  else if (i < n3) { src = w_out; dst = wout_b; off = i - n2; }
  else if (i < n4) { src = w_x;   dst = wx_b;   off = i - n3; }
  else return;
  float4 v = *(const float4*)(src + off);
  u32 lo = (u32)f2b(v.x) | ((u32)f2b(v.y) << 16);
  u32 hi = (u32)f2b(v.z) | ((u32)f2b(v.w) << 16);
  uint2 pk; pk.x = lo; pk.y = hi;
  *(uint2*)(dst + off) = pk;
}

// ---- cast w_dt f32 [DI][48] -> bf16 [DI][64]; col48 = b_dt, col 49..63 = 0 ----
__global__ __launch_bounds__(256) void castwdt(const float* __restrict__ in,
                                               const float* __restrict__ bias,
                                               u16* __restrict__ out) {
  int i = blockIdx.x * 256 + threadIdx.x;   // 0 .. DI*64-1
  int row = i >> 6, col = i & 63;
  float v = (col < 48) ? in[row * 48 + col] : (col == 48 ? bias[row] : 0.f);
  out[i] = f2b(v);
}

// ---------------- 128x128 BT GEMM, BK=32, bf16 MFMA ----------------
// C[m][n] = sum_k A[m][k]*B[n][k].
// CMODE 0: bf16 out, proj layout ((n>>11)*E2+m)*LSEQ+(n&2047).
// CMODE 1: f32 out, row-major m*N+n.
// CMODE 2: bf16 out + fused softplus, layout n*DI+m, LDS-transposed coalesced write.
template<int CMODE>
__global__ __launch_bounds__(256) void gemm_bt(const u16* __restrict__ A,
                                               const u16* __restrict__ B,
                                               void* __restrict__ Cp,
                                               int M, int N, int K) {
  __shared__ __align__(16) u16 a_s[128 * 32];
  __shared__ __align__(16) u16 b_s[128 * 32];
  __shared__ __align__(16) u16 t_s[(CMODE == 2) ? 64 * 128 : 1];
  const int tid = threadIdx.x, lane = tid & 63, w = tid >> 6;
  const int m0 = blockIdx.x * 128, n0 = blockIdx.y * 128;
  const int wm = w >> 1, wn = w & 1;
  f32x4 acc[4][4];
#pragma unroll
  for (int i = 0; i < 4; i++)
#pragma unroll
    for (int j = 0; j < 4; j++) acc[i][j] = (f32x4){0.f, 0.f, 0.f, 0.f};

  const int rA = lane >> 2;
  const int c8 = (lane & 3) * 8;
  const int fr = lane & 15;
  const int fk = (lane >> 4) * 8;

  for (int k0 = 0; k0 < K; k0 += 32) {
#pragma unroll
    for (int j = 0; j < 2; j++) {
      int rr = (w * 2 + j) * 16;
      gld16(A + (size_t)(m0 + rr + rA) * K + k0 + c8, a_s + rr * 32);
      gld16(B + (size_t)(n0 + rr + rA) * K + k0 + c8, b_s + rr * 32);
    }
    __syncthreads();
    bf16x8 af[4], bf[4];
#pragma unroll
    for (int mi = 0; mi < 4; mi++)
      af[mi] = *(const bf16x8*)(a_s + (wm * 64 + mi * 16 + fr) * 32 + fk);
#pragma unroll
    for (int ni = 0; ni < 4; ni++)
      bf[ni] = *(const bf16x8*)(b_s + (wn * 64 + ni * 16 + fr) * 32 + fk);
#pragma unroll
    for (int mi = 0; mi < 4; mi++)
#pragma unroll
      for (int ni = 0; ni < 4; ni++)
        acc[mi][ni] = __builtin_amdgcn_mfma_f32_16x16x32_bf16(
            af[mi], bf[ni], acc[mi][ni], 0, 0, 0);
    __syncthreads();
  }

  const int rbase = (lane >> 4) * 4, cbase = lane & 15;
  if (CMODE == 2) {
    // two passes (wn = 0,1): stage softplus'd bf16 into t_s[n_local 64][m_local 128],
    // then all threads write coalesced [n][m] rows (256 B each).
    u16* dt = (u16*)Cp;
#pragma unroll
    for (int pass = 0; pass < 2; ++pass) {
      if (wn == pass) {
#pragma unroll
        for (int mi = 0; mi < 4; mi++)
#pragma unroll
          for (int ni = 0; ni < 4; ni++)
#pragma unroll
            for (int j = 0; j < 4; j++) {
              int ml = wm * 64 + mi * 16 + rbase + j;
              int nl = ni * 16 + cbase;
              float v = acc[mi][ni][j];
              float sp = (v > 20.f) ? v : log1pf(__expf(v));
              t_s[nl * 128 + ml] = f2b(sp);
            }
      }
      __syncthreads();
      for (int c = tid; c < 64 * 16; c += 256) {
        int nl = c >> 4, q = c & 15;
        int n = n0 + pass * 64 + nl;
        *(uint4*)(dt + (size_t)n * DI + m0 + q * 8) = *(const uint4*)(&t_s[nl * 128 + q * 8]);
      }
      __syncthreads();
    }
    return;
  }
#pragma unroll
  for (int mi = 0; mi < 4; mi++)
#pragma unroll
    for (int ni = 0; ni < 4; ni++)
#pragma unroll
      for (int j = 0; j < 4; j++) {
        int m = m0 + wm * 64 + mi * 16 + rbase + j;
        int n = n0 + wn * 64 + ni * 16 + cbase;
        float v = acc[mi][ni][j];
        if (CMODE == 0) {
          u16* C = (u16*)Cp;
          C[((size_t)(n >> 11) * E2 + m) * LSEQ + (n & 2047)] = f2b(v);
        } else {
          float* C = (float*)Cp;
          C[(size_t)m * N + n] = v;
        }
      }
}

// ---------------- x_proj GEMM: M=80 (staged 128), N-tile 128 ----------------
// Also emits dt-rank rows (m<48) as bf16 into dtin [n][64]; col48=1.0 (bias), 49..63=0.
__global__ __launch_bounds__(256) void gemm_xproj(const u16* __restrict__ A,
                                                  const u16* __restrict__ B,
                                                  float* __restrict__ C,
                                                  u16* __restrict__ dtin) {
  __shared__ __align__(16) u16 a_s[128 * 32];
  __shared__ __align__(16) u16 b_s[128 * 32];
  const int tid = threadIdx.x, lane = tid & 63, w = tid >> 6;
  const int n0 = blockIdx.x * 128;
  const int K = DI;
  f32x4 acc[5][2];
#pragma unroll
  for (int i = 0; i < 5; i++) { acc[i][0] = (f32x4){0,0,0,0}; acc[i][1] = (f32x4){0,0,0,0}; }

  const int rA = lane >> 2;
  const int c8 = (lane & 3) * 8;
  const int fr = lane & 15;
  const int fk = (lane >> 4) * 8;

  for (int k0 = 0; k0 < K; k0 += 32) {
#pragma unroll
    for (int j = 0; j < 2; j++) {
      int rr = (w * 2 + j) * 16;
      gld16(A + (size_t)(rr + rA) * K + k0 + c8, a_s + rr * 32);
      gld16(B + (size_t)(n0 + rr + rA) * K + k0 + c8, b_s + rr * 32);
    }
    __syncthreads();
    bf16x8 af[5], bf[2];
#pragma unroll
    for (int mi = 0; mi < 5; mi++)
      af[mi] = *(const bf16x8*)(a_s + (mi * 16 + fr) * 32 + fk);
#pragma unroll
    for (int ni = 0; ni < 2; ni++)
      bf[ni] = *(const bf16x8*)(b_s + (w * 32 + ni * 16 + fr) * 32 + fk);
#pragma unroll
    for (int mi = 0; mi < 5; mi++)
#pragma unroll
      for (int ni = 0; ni < 2; ni++)
        acc[mi][ni] = __builtin_amdgcn_mfma_f32_16x16x32_bf16(
            af[mi], bf[ni], acc[mi][ni], 0, 0, 0);
    __syncthreads();
  }

  const int rbase = (lane >> 4) * 4, cbase = lane & 15;
#pragma unroll
  for (int mi = 0; mi < 5; mi++)
#pragma unroll
    for (int ni = 0; ni < 2; ni++)
#pragma unroll
      for (int j = 0; j < 4; j++) {
        int m = mi * 16 + rbase + j;
        int n = n0 + w * 32 + ni * 16 + cbase;
        float v = acc[mi][ni][j];
        C[(size_t)n * SSMW + m] = v;
        if (m < 64) {
          u16 dv = (m < 48) ? f2b(v) : (m == 48 ? f2b(1.0f) : (u16)0);
          dtin[(size_t)n * 64 + m] = dv;
        }
      }
}

// ---------------- causal depthwise conv(4) + SiLU ----------------
__global__ __launch_bounds__(256) void conv_silu(const u16* __restrict__ proj,
                                                 const float* __restrict__ cw,
                                                 const float* __restrict__ cb,
                                                 u16* __restrict__ hidden) {
  __shared__ __align__(16) u16 in_s[64][96];
  __shared__ __align__(16) u16 o_s[64][64];
  const int t = threadIdx.x;
  const int d0 = blockIdx.x * 64, l0 = blockIdx.y * 64, bb = blockIdx.z;

  for (int c = t; c < 64 * 12; c += 256) {
    int r = c / 12, q = c % 12;
    int gl = l0 - 32 + q * 8;
    uint4 v;
    if (gl >= 0) v = *(const uint4*)(proj + ((size_t)bb * E2 + d0 + r) * LSEQ + gl);
    else         v = (uint4){0u, 0u, 0u, 0u};
    *(uint4*)(&in_s[r][q * 8]) = v;
  }
  __syncthreads();

  const int dd = t >> 2, ls = t & 3;
  const int d = d0 + dd;
  const float w0 = cw[d * 4 + 0], w1 = cw[d * 4 + 1], w2 = cw[d * 4 + 2], w3 = cw[d * 4 + 3];
  const float bias = cb[d];
#pragma unroll
  for (int i = 0; i < 16; i++) {
    int li = ls * 16 + i;
    int base = 32 + li - 3;
    float h = w0 * b2f(in_s[dd][base + 0]) + w1 * b2f(in_s[dd][base + 1]) +
              w2 * b2f(in_s[dd][base + 2]) + w3 * b2f(in_s[dd][base + 3]) + bias;
    o_s[li][dd] = f2b(silu_f(h));
  }
  __syncthreads();

  for (int c = t; c < 512; c += 256) {
    int r = c >> 3, q = c & 7;
    *(uint4*)(hidden + ((size_t)bb * LSEQ + l0 + r) * DI + d0 + q * 8) =
        *(const uint4*)(&o_s[r][q * 8]);
  }
}

// ================= chunked parallel suffix scan (transposed-LDS, DPP-reduce) =================
__global__ __launch_bounds__(256) void scan_sum(const u16* __restrict__ dt,
                                                const u16* __restrict__ hidden,
                                                const float* __restrict__ ssm,
                                                const float* __restrict__ A_log,
                                                float* __restrict__ gsum,
                                                float* __restrict__ sdt) {
  __shared__ __align__(16) u16 dt_t[16][80];
  __shared__ __align__(16) u16 hid_t[16][80];
  __shared__ __align__(16) float B_t[16][68];
  const int t = threadIdx.x;
  const int d0 = blockIdx.x * 16, c = blockIdx.y, bb = blockIdx.z;
  const int dl = t >> 4, n = t & 15;
  const int d = d0 + dl;
  const int l0 = c * CP;
  {
    int r = t >> 2, q = t & 3;
    size_t lbrow = (size_t)bb * LSEQ + l0 + r;
    uint2 dv = *(const uint2*)(dt + lbrow * DI + d0 + q * 4);
    uint2 hv = *(const uint2*)(hidden + lbrow * DI + d0 + q * 4);
    float4 bv = *(const float4*)(ssm + lbrow * SSMW + 48 + q * 4);
    dt_t[q * 4 + 0][r] = (u16)dv.x;  dt_t[q * 4 + 1][r] = (u16)(dv.x >> 16);
    dt_t[q * 4 + 2][r] = (u16)dv.y;  dt_t[q * 4 + 3][r] = (u16)(dv.y >> 16);
    hid_t[q * 4 + 0][r] = (u16)hv.x; hid_t[q * 4 + 1][r] = (u16)(hv.x >> 16);
    hid_t[q * 4 + 2][r] = (u16)hv.y; hid_t[q * 4 + 3][r] = (u16)(hv.y >> 16);
    B_t[q * 4 + 0][r] = bv.x; B_t[q * 4 + 1][r] = bv.y;
    B_t[q * 4 + 2][r] = bv.z; B_t[q * 4 + 3][r] = bv.w;
  }
  const float An2 = -__expf(A_log[d * 16 + n]) * LOG2E;
  float dt_prev = (c == NC - 1) ? 0.f
                : b2f(dt[((size_t)bb * LSEQ + l0 + CP) * DI + d]);
  __syncthreads();
  float g = 0.f, sumdt = 0.f;
#define STEPS(dtv_, hv_, Bv_) {            \
    float dtv = dtv_;                      \
    float dA = exp2f(An2 * dt_prev);       \
    g = dtv * (Bv_) * (hv_) + dA * g;      \
    sumdt += dt_prev;                      \
    dt_prev = dtv; }
#pragma unroll
  for (int s = 7; s >= 0; --s) {
    uint4 d8 = *(const uint4*)(&dt_t[dl][s * 8]);
    uint4 h8 = *(const uint4*)(&hid_t[dl][s * 8]);
    f32x4 b0 = *(const f32x4*)(&B_t[n][s * 8]);
    f32x4 b1 = *(const f32x4*)(&B_t[n][s * 8 + 4]);
    STEPS(B2F_HI(d8.w), B2F_HI(h8.w), b1[3]);
    STEPS(B2F_LO(d8.w), B2F_LO(h8.w), b1[2]);
    STEPS(B2F_HI(d8.z), B2F_HI(h8.z), b1[1]);
    STEPS(B2F_LO(d8.z), B2F_LO(h8.z), b1[0]);
    STEPS(B2F_HI(d8.y), B2F_HI(h8.y), b0[3]);
    STEPS(B2F_LO(d8.y), B2F_LO(h8.y), b0[2]);
    STEPS(B2F_HI(d8.x), B2F_HI(h8.x), b0[1]);
    STEPS(B2F_LO(d8.x), B2F_LO(h8.x), b0[0]);
  }
#undef STEPS
  size_t idx = (((size_t)bb * NC + c) * DI + d) * 16 + n;
  gsum[idx] = g;
  sdt[idx]  = sumdt;
}

__global__ __launch_bounds__(256) void scan_carry(const float* __restrict__ gsum,
                                                  const float* __restrict__ sdt,
                                                  const float* __restrict__ A_log,
                                                  float* __restrict__ carry) {
  const int t = blockIdx.x * 256 + threadIdx.x;
  const int bb = blockIdx.y;
  const int d = t >> 4, n = t & 15;
  const float An2 = -__expf(A_log[d * 16 + n]) * LOG2E;
  float cg = 0.f;
  carry[(((size_t)bb * NC + NC - 1) * DI + d) * 16 + n] = 0.f;
  for (int c = NC - 2; c >= 0; --c) {
    size_t up = (((size_t)bb * NC + (c + 1)) * DI + d) * 16 + n;
    cg = gsum[up] + exp2f(An2 * sdt[up]) * cg;
    carry[(((size_t)bb * NC + c) * DI + d) * 16 + n] = cg;
  }
}

__global__ __launch_bounds__(256) void scan_apply(const u16* __restrict__ proj,
                                                  const u16* __restrict__ hidden,
                                                  const u16* __restrict__ dt,
                                                  const float* __restrict__ ssm,
                                                  const float* __restrict__ A_log,
                                                  const float* __restrict__ Dp,
                                                  const float* __restrict__ carry,
                                                  u16* __restrict__ y) {
  __shared__ __align__(16) u16 dt_t[16][80];
  __shared__ __align__(16) u16 hid_t[16][80];
  __shared__ __align__(16) u16 gate_t[16][80];
  __shared__ __align__(16) float B_t[16][68];
  __shared__ __align__(16) float C_t[16][68];
  __shared__ __align__(16) u16 y_s[64][16];
  const int t = threadIdx.x;
  const int d0 = blockIdx.x * 16, c = blockIdx.y, bb = blockIdx.z;
  const int dl = t >> 4, n = t & 15;
  const int d = d0 + dl;
  const int l0 = c * CP;
  {
    int r = t >> 2, q = t & 3;
    size_t lbrow = (size_t)bb * LSEQ + l0 + r;
    uint2 dv = *(const uint2*)(dt + lbrow * DI + d0 + q * 4);
    uint2 hv = *(const uint2*)(hidden + lbrow * DI + d0 + q * 4);
    float4 bv = *(const float4*)(ssm + lbrow * SSMW + 48 + q * 4);
    float4 cv = *(const float4*)(ssm + lbrow * SSMW + 64 + q * 4);
    dt_t[q * 4 + 0][r] = (u16)dv.x;  dt_t[q * 4 + 1][r] = (u16)(dv.x >> 16);
    dt_t[q * 4 + 2][r] = (u16)dv.y;  dt_t[q * 4 + 3][r] = (u16)(dv.y >> 16);
    hid_t[q * 4 + 0][r] = (u16)hv.x; hid_t[q * 4 + 1][r] = (u16)(hv.x >> 16);
    hid_t[q * 4 + 2][r] = (u16)hv.y; hid_t[q * 4 + 3][r] = (u16)(hv.y >> 16);
    B_t[q * 4 + 0][r] = bv.x; B_t[q * 4 + 1][r] = bv.y;
    B_t[q * 4 + 2][r] = bv.z; B_t[q * 4 + 3][r] = bv.w;
    C_t[q * 4 + 0][r] = cv.x; C_t[q * 4 + 1][r] = cv.y;
    C_t[q * 4 + 2][r] = cv.z; C_t[q * 4 + 3][r] = cv.w;
  }
  {
    int r = t >> 4, q = t & 15;
    *(uint2*)(&gate_t[r][q * 4]) =
        *(const uint2*)(proj + ((size_t)bb * E2 + DI + d0 + r) * LSEQ + l0 + q * 4);
  }
  const float An2 = -__expf(A_log[d * 16 + n]) * LOG2E;
  const float Dd = Dp[d];
  float g = carry[(((size_t)bb * NC + c) * DI + d) * 16 + n];
  float dt_prev = (c == NC - 1) ? 0.f
                : b2f(dt[((size_t)bb * LSEQ + l0 + CP) * DI + d]);
  __syncthreads();
  float pcap[4] = {0.f, 0.f, 0.f, 0.f};
  float hcap[4] = {0.f, 0.f, 0.f, 0.f};
#define STEPA(IDX, dtv_, hv_, Bv_, Cv_) {                  \
    float dtv = dtv_; float hvv = hv_;                     \
    float dA = exp2f(An2 * dt_prev);                       \
    g = dtv * (Bv_) * hvv + dA * g;                        \
    float p = g * (Cv_);                                   \
    ROWSUM16(p);                                           \
    if (n == ((IDX) & 15)) {                               \
      pcap[(IDX) >> 4] = p; hcap[(IDX) >> 4] = hvv;        \
    }                                                      \
    dt_prev = dtv; }
#pragma unroll
  for (int s = 7; s >= 0; --s) {
    uint4 d8 = *(const uint4*)(&dt_t[dl][s * 8]);
    uint4 h8 = *(const uint4*)(&hid_t[dl][s * 8]);
    f32x4 b0 = *(const f32x4*)(&B_t[n][s * 8]);
    f32x4 b1 = *(const f32x4*)(&B_t[n][s * 8 + 4]);
    f32x4 c0 = *(const f32x4*)(&C_t[n][s * 8]);
    f32x4 c1 = *(const f32x4*)(&C_t[n][s * 8 + 4]);
    STEPA(s * 8 + 7, B2F_HI(d8.w), B2F_HI(h8.w), b1[3], c1[3]);
    STEPA(s * 8 + 6, B2F_LO(d8.w), B2F_LO(h8.w), b1[2], c1[2]);
    STEPA(s * 8 + 5, B2F_HI(d8.z), B2F_HI(h8.z), b1[1], c1[1]);
    STEPA(s * 8 + 4, B2F_LO(d8.z), B2F_LO(h8.z), b1[0], c1[0]);
    STEPA(s * 8 + 3, B2F_HI(d8.y), B2F_HI(h8.y), b0[3], c0[3]);
    STEPA(s * 8 + 2, B2F_LO(d8.y), B2F_LO(h8.y), b0[2], c0[2]);
    STEPA(s * 8 + 1, B2F_HI(d8.x), B2F_HI(h8.x), b0[1], c0[1]);
    STEPA(s * 8 + 0, B2F_LO(d8.x), B2F_LO(h8.x), b0[0], c0[0]);
  }
#undef STEPA
#pragma unroll
  for (int j2 = 0; j2 < 4; ++j2) {
    float gv = b2f(gate_t[dl][n + 16 * j2]);
    float yv = (1.3f * pcap[j2] + hcap[j2] * Dd) * silu_f(gv);
    y_s[n + 16 * j2][dl] = f2b(yv);
  }
  __syncthreads();
  {
    int r = t >> 2, q = t & 3;
    *(uint2*)(y + ((size_t)bb * LSEQ + l0 + r) * DI + d0 + q * 4) =
        *(const uint2*)(&y_s[r][q * 4]);
  }
}

// ---------------- host ----------------
extern "C" void kernel_launch(void* const* d_in, const int* in_sizes, int n_in,
                              void* d_out, int out_size, void* d_ws, size_t ws_size,
                              hipStream_t stream) {
  const float* x_in   = (const float*)d_in[0];
  const float* w_in   = (const float*)d_in[1];
  const float* conv_w = (const float*)d_in[2];
  const float* conv_b = (const float*)d_in[3];
  const float* w_x    = (const float*)d_in[4];
  const float* w_dt   = (const float*)d_in[5];
  const float* b_dt   = (const float*)d_in[6];
  const float* A_log  = (const float*)d_in[7];
  const float* Dp     = (const float*)d_in[8];
  const float* w_out  = (const float*)d_in[9];
  float* outp = (float*)d_out;

  size_t off = 0;
  auto carve = [&](size_t bytes) {
    void* p = (char*)d_ws + off;
    off += (bytes + 255) & ~(size_t)255;
    return p;
  };
  u16*   in_b   = (u16*)  carve((size_t)NLB * DM * 2);
  u16*   win_b  = (u16*)  carve((size_t)E2 * DM * 2);
  u16*   wout_b = (u16*)  carve((size_t)DM * DI * 2);
  u16*   wx_b   = (u16*)  carve((size_t)SSMW * DI * 2);
  u16*   wdtp_b = (u16*)  carve((size_t)DI * 64 * 2);
  u16*   proj_b = (u16*)  carve((size_t)NB * E2 * LSEQ * 2);
  u16*   hid_b  = (u16*)  carve((size_t)NLB * DI * 2);
  float* ssm_b  = (float*)carve((size_t)NLB * SSMW * 4);
  u16*   dtin_b = (u16*)  carve((size_t)NLB * 64 * 2);
  u16*   dt_b   = (u16*)  carve((size_t)NLB * DI * 2);
  u16*   y_b    = (u16*)  carve((size_t)NLB * DI * 2);
  float* gsum_b = (float*)carve((size_t)NB * NC * DI * 16 * 4);
  float* sdt_b  = (float*)carve((size_t)NB * NC * DI * 16 * 4);
  float* car_b  = (float*)carve((size_t)NB * NC * DI * 16 * 4);

  castall<<<(NLB * DM + E2 * DM + DM * DI + SSMW * DI) / 1024, 256, 0, stream>>>(
      x_in, w_in, w_out, w_x, in_b, win_b, wout_b, wx_b);
  castwdt<<<DI * 64 / 256, 256, 0, stream>>>(w_dt, b_dt, wdtp_b);

  gemm_bt<0><<<dim3(E2 / 128, NLB / 128), 256, 0, stream>>>(
      win_b, in_b, proj_b, E2, NLB, DM);
  conv_silu<<<dim3(DI / 64, LSEQ / 64, NB), 256, 0, stream>>>(
      proj_b, conv_w, conv_b, hid_b);
  gemm_xproj<<<NLB / 128, 256, 0, stream>>>(wx_b, hid_b, ssm_b, dtin_b);

  // dt = softplus(dtin @ wdt_pad^T); bias folded via col 48 (wdt=b_dt, dtin=1.0)
  gemm_bt<2><<<dim3(DI / 128, NLB / 128), 256, 0, stream>>>(
      wdtp_b, dtin_b, dt_b, DI, NLB, 64);

  scan_sum<<<dim3(DI / 16, NC, NB), 256, 0, stream>>>(
      dt_b, hid_b, ssm_b, A_log, gsum_b, sdt_b);
  scan_carry<<<dim3(DI * 16 / 256, NB), 256, 0, stream>>>(
      gsum_b, sdt_b, A_log, car_b);
  scan_apply<<<dim3(DI / 16, NC, NB), 256, 0, stream>>>(
      proj_b, hid_b, dt_b, ssm_b, A_log, Dp, car_b, y_b);

  gemm_bt<1><<<dim3(NLB / 128, DM / 128), 256, 0, stream>>>(
      y_b, wout_b, outp, NLB, DM, DI);
}

// Round 9
// 326.191 us; speedup vs baseline: 1.0510x; 1.0510x over previous
//
#include <hip/hip_runtime.h>
#include <hip/hip_bf16.h>

#define DI     1536
#define DM     768
#define E2     3072
#define NST    16
#define LSEQ   2048
#define NB     2
#define NLB    4096
#define SSMW   80
#define DTRANK 48
#define NC     32     // scan chunks
#define CP     64     // chunk length = LSEQ/NC
#define LOG2E  1.44269504f

typedef unsigned short u16;
typedef unsigned int   u32;
typedef __attribute__((ext_vector_type(8))) __bf16 bf16x8;
typedef __attribute__((ext_vector_type(4))) float  f32x4;

__device__ __forceinline__ float b2f(u16 u) {
  union { u32 i; float f; } v; v.i = ((u32)u) << 16; return v.f;
}
__device__ __forceinline__ u16 f2b(float f) {
  union { float f; u32 i; } v; v.f = f;
  u32 r = v.i + 0x7FFFu + ((v.i >> 16) & 1u);
  return (u16)(r >> 16);
}
__device__ __forceinline__ void gld16(const u16* g, u16* l) {
  __builtin_amdgcn_global_load_lds(
      (const __attribute__((address_space(1))) void*)g,
      (__attribute__((address_space(3))) void*)l, 16, 0, 0);
}
__device__ __forceinline__ float silu_f(float x) {
  return x / (1.f + __expf(-x));
}
// raw v_exp_f32 (exp2), no OCML denormal fixup (round-8 lesson: exp2f costs +3 VALU)
__device__ __forceinline__ float fexp2(float x) {
  return __builtin_amdgcn_exp2f(x);
}

#define B2F_LO(w) __uint_as_float(((u32)(w)) << 16)
#define B2F_HI(w) __uint_as_float(((u32)(w)) & 0xFFFF0000u)

// full 16-lane-row sum via DPP rotations; every lane gets the total. Pure VALU.
#define ROWSUM16(p)                                                                               \
  asm("v_add_f32 %0, %1, %2 row_ror:8 row_mask:0xf bank_mask:0xf" : "=v"(p) : "v"(p), "v"(p));    \
  asm("v_add_f32 %0, %1, %2 row_ror:4 row_mask:0xf bank_mask:0xf" : "=v"(p) : "v"(p), "v"(p));    \
  asm("v_add_f32 %0, %1, %2 row_ror:2 row_mask:0xf bank_mask:0xf" : "=v"(p) : "v"(p), "v"(p));    \
  asm("v_add_f32 %0, %1, %2 row_ror:1 row_mask:0xf bank_mask:0xf" : "=v"(p) : "v"(p), "v"(p));

// ---- fused cast f32 -> bf16: x_in, w_in, w_out, w_x, and wdt-pad (col48=b_dt) ----
__global__ __launch_bounds__(256) void castall(const float* __restrict__ x_in,
                                               const float* __restrict__ w_in,
                                               const float* __restrict__ w_out,
                                               const float* __restrict__ w_x,
                                               const float* __restrict__ w_dt,
                                               const float* __restrict__ b_dt,
                                               u16* __restrict__ in_b,
                                               u16* __restrict__ win_b,
                                               u16* __restrict__ wout_b,
                                               u16* __restrict__ wx_b,
                                               u16* __restrict__ wdtp_b) {
  int i = (blockIdx.x * 256 + threadIdx.x) * 4;
  const int n1 = NLB * DM, n2 = n1 + E2 * DM, n3 = n2 + DM * DI, n4 = n3 + SSMW * DI;
  const int n5 = n4 + DI * 64;
  if (i >= n5) return;
  if (i >= n4) {
    // w_dt pad segment: [DI][64]; col<48 from w_dt, col48 = b_dt, col>48 = 0
    int off = i - n4;
    u16 o[4];
#pragma unroll
    for (int j = 0; j < 4; j++) {
      int row = (off + j) >> 6, col = (off + j) & 63;
      float v = (col < 48) ? w_dt[row * 48 + col] : (col == 48 ? b_dt[row] : 0.f);
      o[j] = f2b(v);
    }
    uint2 pk; pk.x = (u32)o[0] | ((u32)o[1] << 16); pk.y = (u32)o[2] | ((u32)o[3] << 16);
    *(uint2*)(wdtp_b + off) = pk;
    return;
  }
  const float* src; u16* dst; int off;
  if (i < n1)      { src = x_in;  dst = in_b;   off = i; }
  else if (i < n2) { src = w_in;  dst = win_b;  off = i - n1; }
  else if (i < n3) { src = w_out; dst = wout_b; off = i - n2; }
  else             { src = w_x;   dst = wx_b;   off = i - n3; }
  float4 v = *(const float4*)(src + off);
  u32 lo = (u32)f2b(v.x) | ((u32)f2b(v.y) << 16);
  u32 hi = (u32)f2b(v.z) | ((u32)f2b(v.w) << 16);
  uint2 pk; pk.x = lo; pk.y = hi;
  *(uint2*)(dst + off) = pk;
}

// ---------------- 128x128 BT GEMM, BK=32, bf16 MFMA ----------------
// C[m][n] = sum_k A[m][k]*B[n][k].
// CMODE 0: bf16 out, proj layout ((n>>11)*E2+m)*LSEQ+(n&2047).
// CMODE 1: f32 out, row-major m*N+n.
// CMODE 2: bf16 out + fused softplus, layout n*DI+m, LDS-transposed coalesced write.
template<int CMODE>
__global__ __launch_bounds__(256) void gemm_bt(const u16* __restrict__ A,
                                               const u16* __restrict__ B,
                                               void* __restrict__ Cp,
                                               int M, int N, int K) {
  __shared__ __align__(16) u16 a_s[128 * 32];
  __shared__ __align__(16) u16 b_s[128 * 32];
  __shared__ __align__(16) u16 t_s[(CMODE == 2) ? 64 * 128 : 1];
  const int tid = threadIdx.x, lane = tid & 63, w = tid >> 6;
  const int m0 = blockIdx.x * 128, n0 = blockIdx.y * 128;
  const int wm = w >> 1, wn = w & 1;
  f32x4 acc[4][4];
#pragma unroll
  for (int i = 0; i < 4; i++)
#pragma unroll
    for (int j = 0; j < 4; j++) acc[i][j] = (f32x4){0.f, 0.f, 0.f, 0.f};

  const int rA = lane >> 2;
  const int c8 = (lane & 3) * 8;
  const int fr = lane & 15;
  const int fk = (lane >> 4) * 8;

  for (int k0 = 0; k0 < K; k0 += 32) {
#pragma unroll
    for (int j = 0; j < 2; j++) {
      int rr = (w * 2 + j) * 16;
      gld16(A + (size_t)(m0 + rr + rA) * K + k0 + c8, a_s + rr * 32);
      gld16(B + (size_t)(n0 + rr + rA) * K + k0 + c8, b_s + rr * 32);
    }
    __syncthreads();
    bf16x8 af[4], bf[4];
#pragma unroll
    for (int mi = 0; mi < 4; mi++)
      af[mi] = *(const bf16x8*)(a_s + (wm * 64 + mi * 16 + fr) * 32 + fk);
#pragma unroll
    for (int ni = 0; ni < 4; ni++)
      bf[ni] = *(const bf16x8*)(b_s + (wn * 64 + ni * 16 + fr) * 32 + fk);
#pragma unroll
    for (int mi = 0; mi < 4; mi++)
#pragma unroll
      for (int ni = 0; ni < 4; ni++)
        acc[mi][ni] = __builtin_amdgcn_mfma_f32_16x16x32_bf16(
            af[mi], bf[ni], acc[mi][ni], 0, 0, 0);
    __syncthreads();
  }

  const int rbase = (lane >> 4) * 4, cbase = lane & 15;
  if (CMODE == 2) {
    u16* dt = (u16*)Cp;
#pragma unroll
    for (int pass = 0; pass < 2; ++pass) {
      if (wn == pass) {
#pragma unroll
        for (int mi = 0; mi < 4; mi++)
#pragma unroll
          for (int ni = 0; ni < 4; ni++)
#pragma unroll
            for (int j = 0; j < 4; j++) {
              int ml = wm * 64 + mi * 16 + rbase + j;
              int nl = ni * 16 + cbase;
              float v = acc[mi][ni][j];
              float sp = (v > 20.f) ? v : log1pf(__expf(v));
              t_s[nl * 128 + ml] = f2b(sp);
            }
      }
      __syncthreads();
      for (int c = tid; c < 64 * 16; c += 256) {
        int nl = c >> 4, q = c & 15;
        int n = n0 + pass * 64 + nl;
        *(uint4*)(dt + (size_t)n * DI + m0 + q * 8) = *(const uint4*)(&t_s[nl * 128 + q * 8]);
      }
      __syncthreads();
    }
    return;
  }
#pragma unroll
  for (int mi = 0; mi < 4; mi++)
#pragma unroll
    for (int ni = 0; ni < 4; ni++)
#pragma unroll
      for (int j = 0; j < 4; j++) {
        int m = m0 + wm * 64 + mi * 16 + rbase + j;
        int n = n0 + wn * 64 + ni * 16 + cbase;
        float v = acc[mi][ni][j];
        if (CMODE == 0) {
          u16* C = (u16*)Cp;
          C[((size_t)(n >> 11) * E2 + m) * LSEQ + (n & 2047)] = f2b(v);
        } else {
          float* C = (float*)Cp;
          C[(size_t)m * N + n] = v;
        }
      }
}

// ---------------- x_proj GEMM: M=80 (staged 128), N-tile 128 ----------------
// Also emits dt-rank rows (m<48) as bf16 into dtin [n][64]; col48=1.0 (bias), 49..63=0.
__global__ __launch_bounds__(256) void gemm_xproj(const u16* __restrict__ A,
                                                  const u16* __restrict__ B,
                                                  float* __restrict__ C,
                                                  u16* __restrict__ dtin) {
  __shared__ __align__(16) u16 a_s[128 * 32];
  __shared__ __align__(16) u16 b_s[128 * 32];
  const int tid = threadIdx.x, lane = tid & 63, w = tid >> 6;
  const int n0 = blockIdx.x * 128;
  const int K = DI;
  f32x4 acc[5][2];
#pragma unroll
  for (int i = 0; i < 5; i++) { acc[i][0] = (f32x4){0,0,0,0}; acc[i][1] = (f32x4){0,0,0,0}; }

  const int rA = lane >> 2;
  const int c8 = (lane & 3) * 8;
  const int fr = lane & 15;
  const int fk = (lane >> 4) * 8;

  for (int k0 = 0; k0 < K; k0 += 32) {
#pragma unroll
    for (int j = 0; j < 2; j++) {
      int rr = (w * 2 + j) * 16;
      gld16(A + (size_t)(rr + rA) * K + k0 + c8, a_s + rr * 32);
      gld16(B + (size_t)(n0 + rr + rA) * K + k0 + c8, b_s + rr * 32);
    }
    __syncthreads();
    bf16x8 af[5], bf[2];
#pragma unroll
    for (int mi = 0; mi < 5; mi++)
      af[mi] = *(const bf16x8*)(a_s + (mi * 16 + fr) * 32 + fk);
#pragma unroll
    for (int ni = 0; ni < 2; ni++)
      bf[ni] = *(const bf16x8*)(b_s + (w * 32 + ni * 16 + fr) * 32 + fk);
#pragma unroll
    for (int mi = 0; mi < 5; mi++)
#pragma unroll
      for (int ni = 0; ni < 2; ni++)
        acc[mi][ni] = __builtin_amdgcn_mfma_f32_16x16x32_bf16(
            af[mi], bf[ni], acc[mi][ni], 0, 0, 0);
    __syncthreads();
  }

  const int rbase = (lane >> 4) * 4, cbase = lane & 15;
#pragma unroll
  for (int mi = 0; mi < 5; mi++)
#pragma unroll
    for (int ni = 0; ni < 2; ni++)
#pragma unroll
      for (int j = 0; j < 4; j++) {
        int m = mi * 16 + rbase + j;
        int n = n0 + w * 32 + ni * 16 + cbase;
        float v = acc[mi][ni][j];
        C[(size_t)n * SSMW + m] = v;
        if (m < 64) {
          u16 dv = (m < 48) ? f2b(v) : (m == 48 ? f2b(1.0f) : (u16)0);
          dtin[(size_t)n * 64 + m] = dv;
        }
      }
}

// ---------------- causal depthwise conv(4) + SiLU ----------------
__global__ __launch_bounds__(256) void conv_silu(const u16* __restrict__ proj,
                                                 const float* __restrict__ cw,
                                                 const float* __restrict__ cb,
                                                 u16* __restrict__ hidden) {
  __shared__ __align__(16) u16 in_s[64][96];
  __shared__ __align__(16) u16 o_s[64][64];
  const int t = threadIdx.x;
  const int d0 = blockIdx.x * 64, l0 = blockIdx.y * 64, bb = blockIdx.z;

  for (int c = t; c < 64 * 12; c += 256) {
    int r = c / 12, q = c % 12;
    int gl = l0 - 32 + q * 8;
    uint4 v;
    if (gl >= 0) v = *(const uint4*)(proj + ((size_t)bb * E2 + d0 + r) * LSEQ + gl);
    else         v = (uint4){0u, 0u, 0u, 0u};
    *(uint4*)(&in_s[r][q * 8]) = v;
  }
  __syncthreads();

  const int dd = t >> 2, ls = t & 3;
  const int d = d0 + dd;
  const float w0 = cw[d * 4 + 0], w1 = cw[d * 4 + 1], w2 = cw[d * 4 + 2], w3 = cw[d * 4 + 3];
  const float bias = cb[d];
#pragma unroll
  for (int i = 0; i < 16; i++) {
    int li = ls * 16 + i;
    int base = 32 + li - 3;
    float h = w0 * b2f(in_s[dd][base + 0]) + w1 * b2f(in_s[dd][base + 1]) +
              w2 * b2f(in_s[dd][base + 2]) + w3 * b2f(in_s[dd][base + 3]) + bias;
    o_s[li][dd] = f2b(silu_f(h));
  }
  __syncthreads();

  for (int c = t; c < 512; c += 256) {
    int r = c >> 3, q = c & 7;
    *(uint4*)(hidden + ((size_t)bb * LSEQ + l0 + r) * DI + d0 + q * 8) =
        *(const uint4*)(&o_s[r][q * 8]);
  }
}

// ================= chunked parallel suffix scan (transposed-LDS, DPP-reduce) =================
__global__ __launch_bounds__(256) void scan_sum(const u16* __restrict__ dt,
                                                const u16* __restrict__ hidden,
                                                const float* __restrict__ ssm,
                                                const float* __restrict__ A_log,
                                                float* __restrict__ gsum,
                                                float* __restrict__ sdt) {
  __shared__ __align__(16) u16 dt_t[16][80];
  __shared__ __align__(16) u16 hid_t[16][80];
  __shared__ __align__(16) float B_t[16][68];
  const int t = threadIdx.x;
  const int d0 = blockIdx.x * 16, c = blockIdx.y, bb = blockIdx.z;
  const int dl = t >> 4, n = t & 15;
  const int d = d0 + dl;
  const int l0 = c * CP;
  {
    int r = t >> 2, q = t & 3;
    size_t lbrow = (size_t)bb * LSEQ + l0 + r;
    uint2 dv = *(const uint2*)(dt + lbrow * DI + d0 + q * 4);
    uint2 hv = *(const uint2*)(hidden + lbrow * DI + d0 + q * 4);
    float4 bv = *(const float4*)(ssm + lbrow * SSMW + 48 + q * 4);
    dt_t[q * 4 + 0][r] = (u16)dv.x;  dt_t[q * 4 + 1][r] = (u16)(dv.x >> 16);
    dt_t[q * 4 + 2][r] = (u16)dv.y;  dt_t[q * 4 + 3][r] = (u16)(dv.y >> 16);
    hid_t[q * 4 + 0][r] = (u16)hv.x; hid_t[q * 4 + 1][r] = (u16)(hv.x >> 16);
    hid_t[q * 4 + 2][r] = (u16)hv.y; hid_t[q * 4 + 3][r] = (u16)(hv.y >> 16);
    B_t[q * 4 + 0][r] = bv.x; B_t[q * 4 + 1][r] = bv.y;
    B_t[q * 4 + 2][r] = bv.z; B_t[q * 4 + 3][r] = bv.w;
  }
  const float An2 = -__expf(A_log[d * 16 + n]) * LOG2E;
  float dt_prev = (c == NC - 1) ? 0.f
                : b2f(dt[((size_t)bb * LSEQ + l0 + CP) * DI + d]);
  __syncthreads();
  float g = 0.f, sumdt = 0.f;
#define STEPS(dtv_, hv_, Bv_) {            \
    float dtv = dtv_;                      \
    float dA = fexp2(An2 * dt_prev);       \
    g = dtv * (Bv_) * (hv_) + dA * g;      \
    sumdt += dt_prev;                      \
    dt_prev = dtv; }
#pragma unroll
  for (int s = 7; s >= 0; --s) {
    uint4 d8 = *(const uint4*)(&dt_t[dl][s * 8]);
    uint4 h8 = *(const uint4*)(&hid_t[dl][s * 8]);
    f32x4 b0 = *(const f32x4*)(&B_t[n][s * 8]);
    f32x4 b1 = *(const f32x4*)(&B_t[n][s * 8 + 4]);
    STEPS(B2F_HI(d8.w), B2F_HI(h8.w), b1[3]);
    STEPS(B2F_LO(d8.w), B2F_LO(h8.w), b1[2]);
    STEPS(B2F_HI(d8.z), B2F_HI(h8.z), b1[1]);
    STEPS(B2F_LO(d8.z), B2F_LO(h8.z), b1[0]);
    STEPS(B2F_HI(d8.y), B2F_HI(h8.y), b0[3]);
    STEPS(B2F_LO(d8.y), B2F_LO(h8.y), b0[2]);
    STEPS(B2F_HI(d8.x), B2F_HI(h8.x), b0[1]);
    STEPS(B2F_LO(d8.x), B2F_LO(h8.x), b0[0]);
  }
#undef STEPS
  size_t idx = (((size_t)bb * NC + c) * DI + d) * 16 + n;
  gsum[idx] = g;
  sdt[idx]  = sumdt;
}

__global__ __launch_bounds__(256) void scan_carry(const float* __restrict__ gsum,
                                                  const float* __restrict__ sdt,
                                                  const float* __restrict__ A_log,
                                                  float* __restrict__ carry) {
  const int t = blockIdx.x * 256 + threadIdx.x;
  const int bb = blockIdx.y;
  const int d = t >> 4, n = t & 15;
  const float An2 = -__expf(A_log[d * 16 + n]) * LOG2E;
  float cg = 0.f;
  carry[(((size_t)bb * NC + NC - 1) * DI + d) * 16 + n] = 0.f;
  for (int c = NC - 2; c >= 0; --c) {
    size_t up = (((size_t)bb * NC + (c + 1)) * DI + d) * 16 + n;
    cg = gsum[up] + fexp2(An2 * sdt[up]) * cg;
    carry[(((size_t)bb * NC + c) * DI + d) * 16 + n] = cg;
  }
}

__global__ __launch_bounds__(256) void scan_apply(const u16* __restrict__ proj,
                                                  const u16* __restrict__ hidden,
                                                  const u16* __restrict__ dt,
                                                  const float* __restrict__ ssm,
                                                  const float* __restrict__ A_log,
                                                  const float* __restrict__ Dp,
                                                  const float* __restrict__ carry,
                                                  u16* __restrict__ y) {
  __shared__ __align__(16) u16 dt_t[16][80];
  __shared__ __align__(16) u16 hid_t[16][80];
  __shared__ __align__(16) u16 gate_t[16][80];
  __shared__ __align__(16) float B_t[16][68];
  __shared__ __align__(16) float C_t[16][68];
  __shared__ __align__(16) u16 y_s[64][16];
  const int t = threadIdx.x;
  const int d0 = blockIdx.x * 16, c = blockIdx.y, bb = blockIdx.z;
  const int dl = t >> 4, n = t & 15;
  const int d = d0 + dl;
  const int l0 = c * CP;
  {
    int r = t >> 2, q = t & 3;
    size_t lbrow = (size_t)bb * LSEQ + l0 + r;
    uint2 dv = *(const uint2*)(dt + lbrow * DI + d0 + q * 4);
    uint2 hv = *(const uint2*)(hidden + lbrow * DI + d0 + q * 4);
    float4 bv = *(const float4*)(ssm + lbrow * SSMW + 48 + q * 4);
    float4 cv = *(const float4*)(ssm + lbrow * SSMW + 64 + q * 4);
    dt_t[q * 4 + 0][r] = (u16)dv.x;  dt_t[q * 4 + 1][r] = (u16)(dv.x >> 16);
    dt_t[q * 4 + 2][r] = (u16)dv.y;  dt_t[q * 4 + 3][r] = (u16)(dv.y >> 16);
    hid_t[q * 4 + 0][r] = (u16)hv.x; hid_t[q * 4 + 1][r] = (u16)(hv.x >> 16);
    hid_t[q * 4 + 2][r] = (u16)hv.y; hid_t[q * 4 + 3][r] = (u16)(hv.y >> 16);
    B_t[q * 4 + 0][r] = bv.x; B_t[q * 4 + 1][r] = bv.y;
    B_t[q * 4 + 2][r] = bv.z; B_t[q * 4 + 3][r] = bv.w;
    C_t[q * 4 + 0][r] = cv.x; C_t[q * 4 + 1][r] = cv.y;
    C_t[q * 4 + 2][r] = cv.z; C_t[q * 4 + 3][r] = cv.w;
  }
  {
    int r = t >> 4, q = t & 15;
    *(uint2*)(&gate_t[r][q * 4]) =
        *(const uint2*)(proj + ((size_t)bb * E2 + DI + d0 + r) * LSEQ + l0 + q * 4);
  }
  const float An2 = -__expf(A_log[d * 16 + n]) * LOG2E;
  const float Dd = Dp[d];
  float g = carry[(((size_t)bb * NC + c) * DI + d) * 16 + n];
  float dt_prev = (c == NC - 1) ? 0.f
                : b2f(dt[((size_t)bb * LSEQ + l0 + CP) * DI + d]);
  __syncthreads();
  float pcap[4] = {0.f, 0.f, 0.f, 0.f};
  float hcap[4] = {0.f, 0.f, 0.f, 0.f};
#define STEPA(IDX, dtv_, hv_, Bv_, Cv_) {                  \
    float dtv = dtv_; float hvv = hv_;                     \
    float dA = fexp2(An2 * dt_prev);                       \
    g = dtv * (Bv_) * hvv + dA * g;                        \
    float p = g * (Cv_);                                   \
    ROWSUM16(p);                                           \
    if (n == ((IDX) & 15)) {                               \
      pcap[(IDX) >> 4] = p; hcap[(IDX) >> 4] = hvv;        \
    }                                                      \
    dt_prev = dtv; }
#pragma unroll
  for (int s = 7; s >= 0; --s) {
    uint4 d8 = *(const uint4*)(&dt_t[dl][s * 8]);
    uint4 h8 = *(const uint4*)(&hid_t[dl][s * 8]);
    f32x4 b0 = *(const f32x4*)(&B_t[n][s * 8]);
    f32x4 b1 = *(const f32x4*)(&B_t[n][s * 8 + 4]);
    f32x4 c0 = *(const f32x4*)(&C_t[n][s * 8]);
    f32x4 c1 = *(const f32x4*)(&C_t[n][s * 8 + 4]);
    STEPA(s * 8 + 7, B2F_HI(d8.w), B2F_HI(h8.w), b1[3], c1[3]);
    STEPA(s * 8 + 6, B2F_LO(d8.w), B2F_LO(h8.w), b1[2], c1[2]);
    STEPA(s * 8 + 5, B2F_HI(d8.z), B2F_HI(h8.z), b1[1], c1[1]);
    STEPA(s * 8 + 4, B2F_LO(d8.z), B2F_LO(h8.z), b1[0], c1[0]);
    STEPA(s * 8 + 3, B2F_HI(d8.y), B2F_HI(h8.y), b0[3], c0[3]);
    STEPA(s * 8 + 2, B2F_LO(d8.y), B2F_LO(h8.y), b0[2], c0[2]);
    STEPA(s * 8 + 1, B2F_HI(d8.x), B2F_HI(h8.x), b0[1], c0[1]);
    STEPA(s * 8 + 0, B2F_LO(d8.x), B2F_LO(h8.x), b0[0], c0[0]);
  }
#undef STEPA
#pragma unroll
  for (int j2 = 0; j2 < 4; ++j2) {
    float gv = b2f(gate_t[dl][n + 16 * j2]);
    float yv = (1.3f * pcap[j2] + hcap[j2] * Dd) * silu_f(gv);
    y_s[n + 16 * j2][dl] = f2b(yv);
  }
  __syncthreads();
  {
    int r = t >> 2, q = t & 3;
    *(uint2*)(y + ((size_t)bb * LSEQ + l0 + r) * DI + d0 + q * 4) =
        *(const uint2*)(&y_s[r][q * 4]);
  }
}

// ---------------- host ----------------
extern "C" void kernel_launch(void* const* d_in, const int* in_sizes, int n_in,
                              void* d_out, int out_size, void* d_ws, size_t ws_size,
                              hipStream_t stream) {
  const float* x_in   = (const float*)d_in[0];
  const float* w_in   = (const float*)d_in[1];
  const float* conv_w = (const float*)d_in[2];
  const float* conv_b = (const float*)d_in[3];
  const float* w_x    = (const float*)d_in[4];
  const float* w_dt   = (const float*)d_in[5];
  const float* b_dt   = (const float*)d_in[6];
  const float* A_log  = (const float*)d_in[7];
  const float* Dp     = (const float*)d_in[8];
  const float* w_out  = (const float*)d_in[9];
  float* outp = (float*)d_out;

  size_t off = 0;
  auto carve = [&](size_t bytes) {
    void* p = (char*)d_ws + off;
    off += (bytes + 255) & ~(size_t)255;
    return p;
  };
  u16*   in_b   = (u16*)  carve((size_t)NLB * DM * 2);
  u16*   win_b  = (u16*)  carve((size_t)E2 * DM * 2);
  u16*   wout_b = (u16*)  carve((size_t)DM * DI * 2);
  u16*   wx_b   = (u16*)  carve((size_t)SSMW * DI * 2);
  u16*   wdtp_b = (u16*)  carve((size_t)DI * 64 * 2);
  u16*   proj_b = (u16*)  carve((size_t)NB * E2 * LSEQ * 2);
  u16*   hid_b  = (u16*)  carve((size_t)NLB * DI * 2);
  float* ssm_b  = (float*)carve((size_t)NLB * SSMW * 4);
  u16*   dtin_b = (u16*)  carve((size_t)NLB * 64 * 2);
  u16*   dt_b   = (u16*)  carve((size_t)NLB * DI * 2);
  u16*   y_b    = (u16*)  carve((size_t)NLB * DI * 2);
  float* gsum_b = (float*)carve((size_t)NB * NC * DI * 16 * 4);
  float* sdt_b  = (float*)carve((size_t)NB * NC * DI * 16 * 4);
  float* car_b  = (float*)carve((size_t)NB * NC * DI * 16 * 4);

  const int ncast = NLB * DM + E2 * DM + DM * DI + SSMW * DI + DI * 64;
  castall<<<(ncast + 1023) / 1024, 256, 0, stream>>>(
      x_in, w_in, w_out, w_x, w_dt, b_dt, in_b, win_b, wout_b, wx_b, wdtp_b);

  gemm_bt<0><<<dim3(E2 / 128, NLB / 128), 256, 0, stream>>>(
      win_b, in_b, proj_b, E2, NLB, DM);
  conv_silu<<<dim3(DI / 64, LSEQ / 64, NB), 256, 0, stream>>>(
      proj_b, conv_w, conv_b, hid_b);
  gemm_xproj<<<NLB / 128, 256, 0, stream>>>(wx_b, hid_b, ssm_b, dtin_b);

  // dt = softplus(dtin @ wdt_pad^T); bias folded via col 48 (wdt=b_dt, dtin=1.0)
  gemm_bt<2><<<dim3(DI / 128, NLB / 128), 256, 0, stream>>>(
      wdtp_b, dtin_b, dt_b, DI, NLB, 64);

  scan_sum<<<dim3(DI / 16, NC, NB), 256, 0, stream>>>(
      dt_b, hid_b, ssm_b, A_log, gsum_b, sdt_b);
  scan_carry<<<dim3(DI * 16 / 256, NB), 256, 0, stream>>>(
      gsum_b, sdt_b, A_log, car_b);
  scan_apply<<<dim3(DI / 16, NC, NB), 256, 0, stream>>>(
      proj_b, hid_b, dt_b, ssm_b, A_log, Dp, car_b, y_b);

  gemm_bt<1><<<dim3(NLB / 128, DM / 128), 256, 0, stream>>>(
      y_b, wout_b, outp, NLB, DM, DI);
}

// Round 10
// 297.978 us; speedup vs baseline: 1.1505x; 1.0947x over previous
//
#include <hip/hip_runtime.h>
#include <hip/hip_bf16.h>

#define DI     1536
#define DM     768
#define E2     3072
#define NST    16
#define LSEQ   2048
#define NB     2
#define NLB    4096
#define SSMW   80
#define DTRANK 48
#define NC     32     // scan chunks
#define CP     64     // chunk length = LSEQ/NC
#define LOG2E  1.44269504f
#define RLOG2E 0.69314718f

typedef unsigned short u16;
typedef unsigned int   u32;
typedef __attribute__((ext_vector_type(8))) __bf16 bf16x8;
typedef __attribute__((ext_vector_type(4))) float  f32x4;

__device__ __forceinline__ float b2f(u16 u) {
  union { u32 i; float f; } v; v.i = ((u32)u) << 16; return v.f;
}
__device__ __forceinline__ u16 f2b(float f) {
  union { float f; u32 i; } v; v.f = f;
  u32 r = v.i + 0x7FFFu + ((v.i >> 16) & 1u);
  return (u16)(r >> 16);
}
__device__ __forceinline__ void gld16(const u16* g, u16* l) {
  __builtin_amdgcn_global_load_lds(
      (const __attribute__((address_space(1))) void*)g,
      (__attribute__((address_space(3))) void*)l, 16, 0, 0);
}
__device__ __forceinline__ float silu_f(float x) {
  return x / (1.f + __expf(-x));
}
// raw v_exp_f32 / v_log_f32 (no OCML denormal fixup; round-8 lesson)
__device__ __forceinline__ float fexp2(float x) { return __builtin_amdgcn_exp2f(x); }
__device__ __forceinline__ float flog2(float x) { return __builtin_amdgcn_logf(x); }
// softplus = log2(1 + 2^(x*log2e)) / log2e ; guard keeps large x exact
__device__ __forceinline__ float softplus_f(float x) {
  return (x > 20.f) ? x : flog2(1.f + fexp2(x * LOG2E)) * RLOG2E;
}

#define B2F_LO(w) __uint_as_float(((u32)(w)) << 16)
#define B2F_HI(w) __uint_as_float(((u32)(w)) & 0xFFFF0000u)

// full 16-lane-row sum via DPP rotations; every lane gets the total. Pure VALU.
#define ROWSUM16(p)                                                                               \
  asm("v_add_f32 %0, %1, %2 row_ror:8 row_mask:0xf bank_mask:0xf" : "=v"(p) : "v"(p), "v"(p));    \
  asm("v_add_f32 %0, %1, %2 row_ror:4 row_mask:0xf bank_mask:0xf" : "=v"(p) : "v"(p), "v"(p));    \
  asm("v_add_f32 %0, %1, %2 row_ror:2 row_mask:0xf bank_mask:0xf" : "=v"(p) : "v"(p), "v"(p));    \
  asm("v_add_f32 %0, %1, %2 row_ror:1 row_mask:0xf bank_mask:0xf" : "=v"(p) : "v"(p), "v"(p));

// ---- fused cast f32 -> bf16: x_in, w_in, w_out, w_x, and wdt-pad (col48=b_dt) ----
__global__ __launch_bounds__(256) void castall(const float* __restrict__ x_in,
                                               const float* __restrict__ w_in,
                                               const float* __restrict__ w_out,
                                               const float* __restrict__ w_x,
                                               const float* __restrict__ w_dt,
                                               const float* __restrict__ b_dt,
                                               u16* __restrict__ in_b,
                                               u16* __restrict__ win_b,
                                               u16* __restrict__ wout_b,
                                               u16* __restrict__ wx_b,
                                               u16* __restrict__ wdtp_b) {
  int i = (blockIdx.x * 256 + threadIdx.x) * 4;
  const int n1 = NLB * DM, n2 = n1 + E2 * DM, n3 = n2 + DM * DI, n4 = n3 + SSMW * DI;
  const int n5 = n4 + DI * 64;
  if (i >= n5) return;
  if (i >= n4) {
    int off = i - n4;
    u16 o[4];
#pragma unroll
    for (int j = 0; j < 4; j++) {
      int row = (off + j) >> 6, col = (off + j) & 63;
      float v = (col < 48) ? w_dt[row * 48 + col] : (col == 48 ? b_dt[row] : 0.f);
      o[j] = f2b(v);
    }
    uint2 pk; pk.x = (u32)o[0] | ((u32)o[1] << 16); pk.y = (u32)o[2] | ((u32)o[3] << 16);
    *(uint2*)(wdtp_b + off) = pk;
    return;
  }
  const float* src; u16* dst; int off;
  if (i < n1)      { src = x_in;  dst = in_b;   off = i; }
  else if (i < n2) { src = w_in;  dst = win_b;  off = i - n1; }
  else if (i < n3) { src = w_out; dst = wout_b; off = i - n2; }
  else             { src = w_x;   dst = wx_b;   off = i - n3; }
  float4 v = *(const float4*)(src + off);
  u32 lo = (u32)f2b(v.x) | ((u32)f2b(v.y) << 16);
  u32 hi = (u32)f2b(v.z) | ((u32)f2b(v.w) << 16);
  uint2 pk; pk.x = lo; pk.y = hi;
  *(uint2*)(dst + off) = pk;
}

// ---------------- 128x128 BT GEMM, BK=32, bf16 MFMA ----------------
// C[m][n] = sum_k A[m][k]*B[n][k].
// CMODE 0: bf16 out, proj layout ((n>>11)*E2+m)*LSEQ+(n&2047).
// CMODE 1: f32 out, row-major m*N+n.
template<int CMODE>
__global__ __launch_bounds__(256) void gemm_bt(const u16* __restrict__ A,
                                               const u16* __restrict__ B,
                                               void* __restrict__ Cp,
                                               int M, int N, int K) {
  __shared__ __align__(16) u16 a_s[128 * 32];
  __shared__ __align__(16) u16 b_s[128 * 32];
  const int tid = threadIdx.x, lane = tid & 63, w = tid >> 6;
  const int m0 = blockIdx.x * 128, n0 = blockIdx.y * 128;
  const int wm = w >> 1, wn = w & 1;
  f32x4 acc[4][4];
#pragma unroll
  for (int i = 0; i < 4; i++)
#pragma unroll
    for (int j = 0; j < 4; j++) acc[i][j] = (f32x4){0.f, 0.f, 0.f, 0.f};

  const int rA = lane >> 2;
  const int c8 = (lane & 3) * 8;
  const int fr = lane & 15;
  const int fk = (lane >> 4) * 8;

  for (int k0 = 0; k0 < K; k0 += 32) {
#pragma unroll
    for (int j = 0; j < 2; j++) {
      int rr = (w * 2 + j) * 16;
      gld16(A + (size_t)(m0 + rr + rA) * K + k0 + c8, a_s + rr * 32);
      gld16(B + (size_t)(n0 + rr + rA) * K + k0 + c8, b_s + rr * 32);
    }
    __syncthreads();
    bf16x8 af[4], bf[4];
#pragma unroll
    for (int mi = 0; mi < 4; mi++)
      af[mi] = *(const bf16x8*)(a_s + (wm * 64 + mi * 16 + fr) * 32 + fk);
#pragma unroll
    for (int ni = 0; ni < 4; ni++)
      bf[ni] = *(const bf16x8*)(b_s + (wn * 64 + ni * 16 + fr) * 32 + fk);
#pragma unroll
    for (int mi = 0; mi < 4; mi++)
#pragma unroll
      for (int ni = 0; ni < 4; ni++)
        acc[mi][ni] = __builtin_amdgcn_mfma_f32_16x16x32_bf16(
            af[mi], bf[ni], acc[mi][ni], 0, 0, 0);
    __syncthreads();
  }

  const int rbase = (lane >> 4) * 4, cbase = lane & 15;
#pragma unroll
  for (int mi = 0; mi < 4; mi++)
#pragma unroll
    for (int ni = 0; ni < 4; ni++)
#pragma unroll
      for (int j = 0; j < 4; j++) {
        int m = m0 + wm * 64 + mi * 16 + rbase + j;
        int n = n0 + wn * 64 + ni * 16 + cbase;
        float v = acc[mi][ni][j];
        if (CMODE == 0) {
          u16* C = (u16*)Cp;
          C[((size_t)(n >> 11) * E2 + m) * LSEQ + (n & 2047)] = f2b(v);
        } else {
          float* C = (float*)Cp;
          C[(size_t)m * N + n] = v;
        }
      }
}

// ---------------- x_proj GEMM: M=80 (staged 128), N-tile 128 ----------------
// Also emits dt-rank rows (m<48) as bf16 into dtin [n][64]; col48=1.0 (bias), 49..63=0.
__global__ __launch_bounds__(256) void gemm_xproj(const u16* __restrict__ A,
                                                  const u16* __restrict__ B,
                                                  float* __restrict__ C,
                                                  u16* __restrict__ dtin) {
  __shared__ __align__(16) u16 a_s[128 * 32];
  __shared__ __align__(16) u16 b_s[128 * 32];
  const int tid = threadIdx.x, lane = tid & 63, w = tid >> 6;
  const int n0 = blockIdx.x * 128;
  const int K = DI;
  f32x4 acc[5][2];
#pragma unroll
  for (int i = 0; i < 5; i++) { acc[i][0] = (f32x4){0,0,0,0}; acc[i][1] = (f32x4){0,0,0,0}; }

  const int rA = lane >> 2;
  const int c8 = (lane & 3) * 8;
  const int fr = lane & 15;
  const int fk = (lane >> 4) * 8;

  for (int k0 = 0; k0 < K; k0 += 32) {
#pragma unroll
    for (int j = 0; j < 2; j++) {
      int rr = (w * 2 + j) * 16;
      gld16(A + (size_t)(rr + rA) * K + k0 + c8, a_s + rr * 32);
      gld16(B + (size_t)(n0 + rr + rA) * K + k0 + c8, b_s + rr * 32);
    }
    __syncthreads();
    bf16x8 af[5], bf[2];
#pragma unroll
    for (int mi = 0; mi < 5; mi++)
      af[mi] = *(const bf16x8*)(a_s + (mi * 16 + fr) * 32 + fk);
#pragma unroll
    for (int ni = 0; ni < 2; ni++)
      bf[ni] = *(const bf16x8*)(b_s + (w * 32 + ni * 16 + fr) * 32 + fk);
#pragma unroll
    for (int mi = 0; mi < 5; mi++)
#pragma unroll
      for (int ni = 0; ni < 2; ni++)
        acc[mi][ni] = __builtin_amdgcn_mfma_f32_16x16x32_bf16(
            af[mi], bf[ni], acc[mi][ni], 0, 0, 0);
    __syncthreads();
  }

  const int rbase = (lane >> 4) * 4, cbase = lane & 15;
#pragma unroll
  for (int mi = 0; mi < 5; mi++)
#pragma unroll
    for (int ni = 0; ni < 2; ni++)
#pragma unroll
      for (int j = 0; j < 4; j++) {
        int m = mi * 16 + rbase + j;
        int n = n0 + w * 32 + ni * 16 + cbase;
        float v = acc[mi][ni][j];
        C[(size_t)n * SSMW + m] = v;
        if (m < 64) {
          u16 dv = (m < 48) ? f2b(v) : (m == 48 ? f2b(1.0f) : (u16)0);
          dtin[(size_t)n * 64 + m] = dv;
        }
      }
}

// ---------------- causal depthwise conv(4) + SiLU ----------------
__global__ __launch_bounds__(256) void conv_silu(const u16* __restrict__ proj,
                                                 const float* __restrict__ cw,
                                                 const float* __restrict__ cb,
                                                 u16* __restrict__ hidden) {
  __shared__ __align__(16) u16 in_s[64][96];
  __shared__ __align__(16) u16 o_s[64][64];
  const int t = threadIdx.x;
  const int d0 = blockIdx.x * 64, l0 = blockIdx.y * 64, bb = blockIdx.z;

  for (int c = t; c < 64 * 12; c += 256) {
    int r = c / 12, q = c % 12;
    int gl = l0 - 32 + q * 8;
    uint4 v;
    if (gl >= 0) v = *(const uint4*)(proj + ((size_t)bb * E2 + d0 + r) * LSEQ + gl);
    else         v = (uint4){0u, 0u, 0u, 0u};
    *(uint4*)(&in_s[r][q * 8]) = v;
  }
  __syncthreads();

  const int dd = t >> 2, ls = t & 3;
  const int d = d0 + dd;
  const float w0 = cw[d * 4 + 0], w1 = cw[d * 4 + 1], w2 = cw[d * 4 + 2], w3 = cw[d * 4 + 3];
  const float bias = cb[d];
#pragma unroll
  for (int i = 0; i < 16; i++) {
    int li = ls * 16 + i;
    int base = 32 + li - 3;
    float h = w0 * b2f(in_s[dd][base + 0]) + w1 * b2f(in_s[dd][base + 1]) +
              w2 * b2f(in_s[dd][base + 2]) + w3 * b2f(in_s[dd][base + 3]) + bias;
    o_s[li][dd] = f2b(silu_f(h));
  }
  __syncthreads();

  for (int c = t; c < 512; c += 256) {
    int r = c >> 3, q = c & 7;
    *(uint4*)(hidden + ((size_t)bb * LSEQ + l0 + r) * DI + d0 + q * 8) =
        *(const uint4*)(&o_s[r][q * 8]);
  }
}

// ================= chunked parallel suffix scan, dt fused via MFMA =================
// dt tile [l0..l0+79][d0..d0+15] = softplus(dtin(K=64) . wdtp^T), computed in-block:
// 5 m-tiles x 2 MFMAs, split across 4 waves; stored transposed into dt_t[16][80].

#define DT_TILE_MFMA(dtin, wdtp)                                                          \
  {                                                                                       \
    const u16* ar = dtin + ((size_t)bb * LSEQ + l0) * 64;                                 \
    bf16x8 wb0 = *(const bf16x8*)(wdtp + (size_t)(d0 + fr) * 64 + fk);                    \
    bf16x8 wb1 = *(const bf16x8*)(wdtp + (size_t)(d0 + fr) * 64 + 32 + fk);               \
    for (int mt = wv; mt < 5; mt += 4) {                                                  \
      bf16x8 a0 = *(const bf16x8*)(ar + (size_t)(mt * 16 + fr) * 64 + fk);                \
      bf16x8 a1 = *(const bf16x8*)(ar + (size_t)(mt * 16 + fr) * 64 + 32 + fk);           \
      f32x4 da = (f32x4){0.f, 0.f, 0.f, 0.f};                                             \
      da = __builtin_amdgcn_mfma_f32_16x16x32_bf16(a0, wb0, da, 0, 0, 0);                 \
      da = __builtin_amdgcn_mfma_f32_16x16x32_bf16(a1, wb1, da, 0, 0, 0);                 \
      _Pragma("unroll")                                                                   \
      for (int j = 0; j < 4; j++)                                                         \
        dt_t[cbase][mt * 16 + rbase + j] = f2b(softplus_f(da[j]));                        \
    }                                                                                     \
  }

// Phase A: per-chunk local summary -> gsum (g_local at l0), sdt (sum dt over (l0,l1])
__global__ __launch_bounds__(256) void scan_sum(const u16* __restrict__ dtin,
                                                const u16* __restrict__ wdtp,
                                                const u16* __restrict__ hidden,
                                                const float* __restrict__ ssm,
                                                const float* __restrict__ A_log,
                                                float* __restrict__ gsum,
                                                float* __restrict__ sdt) {
  __shared__ __align__(16) u16 dt_t[16][80];
  __shared__ __align__(16) u16 hid_t[16][80];
  __shared__ __align__(16) float B_t[16][68];
  const int t = threadIdx.x;
  const int d0 = blockIdx.x * 16, c = blockIdx.y, bb = blockIdx.z;
  const int dl = t >> 4, n = t & 15;
  const int d = d0 + dl;
  const int l0 = c * CP;
  const int lane = t & 63, wv = t >> 6;
  const int fr = lane & 15, fk = (lane >> 4) * 8;
  const int rbase = (lane >> 4) * 4, cbase = lane & 15;
  {
    int r = t >> 2, q = t & 3;
    size_t lbrow = (size_t)bb * LSEQ + l0 + r;
    uint2 hv = *(const uint2*)(hidden + lbrow * DI + d0 + q * 4);
    float4 bv = *(const float4*)(ssm + lbrow * SSMW + 48 + q * 4);
    hid_t[q * 4 + 0][r] = (u16)hv.x; hid_t[q * 4 + 1][r] = (u16)(hv.x >> 16);
    hid_t[q * 4 + 2][r] = (u16)hv.y; hid_t[q * 4 + 3][r] = (u16)(hv.y >> 16);
    B_t[q * 4 + 0][r] = bv.x; B_t[q * 4 + 1][r] = bv.y;
    B_t[q * 4 + 2][r] = bv.z; B_t[q * 4 + 3][r] = bv.w;
  }
  DT_TILE_MFMA(dtin, wdtp)
  const float An2 = -__expf(A_log[d * 16 + n]) * LOG2E;
  __syncthreads();
  float dt_prev = (c == NC - 1) ? 0.f : b2f(dt_t[dl][64]);
  float g = 0.f, sumdt = 0.f;
#define STEPS(dtv_, hv_, Bv_) {            \
    float dtv = dtv_;                      \
    float dA = fexp2(An2 * dt_prev);       \
    g = dtv * (Bv_) * (hv_) + dA * g;      \
    sumdt += dt_prev;                      \
    dt_prev = dtv; }
#pragma unroll
  for (int s = 7; s >= 0; --s) {
    uint4 d8 = *(const uint4*)(&dt_t[dl][s * 8]);
    uint4 h8 = *(const uint4*)(&hid_t[dl][s * 8]);
    f32x4 b0 = *(const f32x4*)(&B_t[n][s * 8]);
    f32x4 b1 = *(const f32x4*)(&B_t[n][s * 8 + 4]);
    STEPS(B2F_HI(d8.w), B2F_HI(h8.w), b1[3]);
    STEPS(B2F_LO(d8.w), B2F_LO(h8.w), b1[2]);
    STEPS(B2F_HI(d8.z), B2F_HI(h8.z), b1[1]);
    STEPS(B2F_LO(d8.z), B2F_LO(h8.z), b1[0]);
    STEPS(B2F_HI(d8.y), B2F_HI(h8.y), b0[3]);
    STEPS(B2F_LO(d8.y), B2F_LO(h8.y), b0[2]);
    STEPS(B2F_HI(d8.x), B2F_HI(h8.x), b0[1]);
    STEPS(B2F_LO(d8.x), B2F_LO(h8.x), b0[0]);
  }
#undef STEPS
  size_t idx = (((size_t)bb * NC + c) * DI + d) * 16 + n;
  gsum[idx] = g;
  sdt[idx]  = sumdt;
}

// Phase B: serial combine over 32 chunk summaries -> carry[c]
__global__ __launch_bounds__(256) void scan_carry(const float* __restrict__ gsum,
                                                  const float* __restrict__ sdt,
                                                  const float* __restrict__ A_log,
                                                  float* __restrict__ carry) {
  const int t = blockIdx.x * 256 + threadIdx.x;
  const int bb = blockIdx.y;
  const int d = t >> 4, n = t & 15;
  const float An2 = -__expf(A_log[d * 16 + n]) * LOG2E;
  float cg = 0.f;
  carry[(((size_t)bb * NC + NC - 1) * DI + d) * 16 + n] = 0.f;
  for (int c = NC - 2; c >= 0; --c) {
    size_t up = (((size_t)bb * NC + (c + 1)) * DI + d) * 16 + n;
    cg = gsum[up] + fexp2(An2 * sdt[up]) * cg;
    carry[(((size_t)bb * NC + c) * DI + d) * 16 + n] = cg;
  }
}

// Phase C: re-run local scan seeded with carry; fuse C-proj, D, gating -> y
__global__ __launch_bounds__(256) void scan_apply(const u16* __restrict__ proj,
                                                  const u16* __restrict__ hidden,
                                                  const u16* __restrict__ dtin,
                                                  const u16* __restrict__ wdtp,
                                                  const float* __restrict__ ssm,
                                                  const float* __restrict__ A_log,
                                                  const float* __restrict__ Dp,
                                                  const float* __restrict__ carry,
                                                  u16* __restrict__ y) {
  __shared__ __align__(16) u16 dt_t[16][80];
  __shared__ __align__(16) u16 hid_t[16][80];
  __shared__ __align__(16) u16 gate_t[16][80];
  __shared__ __align__(16) float B_t[16][68];
  __shared__ __align__(16) float C_t[16][68];
  __shared__ __align__(16) u16 y_s[64][16];
  const int t = threadIdx.x;
  const int d0 = blockIdx.x * 16, c = blockIdx.y, bb = blockIdx.z;
  const int dl = t >> 4, n = t & 15;
  const int d = d0 + dl;
  const int l0 = c * CP;
  const int lane = t & 63, wv = t >> 6;
  const int fr = lane & 15, fk = (lane >> 4) * 8;
  const int rbase = (lane >> 4) * 4, cbase = lane & 15;
  {
    int r = t >> 2, q = t & 3;
    size_t lbrow = (size_t)bb * LSEQ + l0 + r;
    uint2 hv = *(const uint2*)(hidden + lbrow * DI + d0 + q * 4);
    float4 bv = *(const float4*)(ssm + lbrow * SSMW + 48 + q * 4);
    float4 cv = *(const float4*)(ssm + lbrow * SSMW + 64 + q * 4);
    hid_t[q * 4 + 0][r] = (u16)hv.x; hid_t[q * 4 + 1][r] = (u16)(hv.x >> 16);
    hid_t[q * 4 + 2][r] = (u16)hv.y; hid_t[q * 4 + 3][r] = (u16)(hv.y >> 16);
    B_t[q * 4 + 0][r] = bv.x; B_t[q * 4 + 1][r] = bv.y;
    B_t[q * 4 + 2][r] = bv.z; B_t[q * 4 + 3][r] = bv.w;
    C_t[q * 4 + 0][r] = cv.x; C_t[q * 4 + 1][r] = cv.y;
    C_t[q * 4 + 2][r] = cv.z; C_t[q * 4 + 3][r] = cv.w;
  }
  {
    int r = t >> 4, q = t & 15;
    *(uint2*)(&gate_t[r][q * 4]) =
        *(const uint2*)(proj + ((size_t)bb * E2 + DI + d0 + r) * LSEQ + l0 + q * 4);
  }
  DT_TILE_MFMA(dtin, wdtp)
  const float An2 = -__expf(A_log[d * 16 + n]) * LOG2E;
  const float Dd = Dp[d];
  float g = carry[(((size_t)bb * NC + c) * DI + d) * 16 + n];
  __syncthreads();
  float dt_prev = (c == NC - 1) ? 0.f : b2f(dt_t[dl][64]);
  float pcap[4] = {0.f, 0.f, 0.f, 0.f};
  float hcap[4] = {0.f, 0.f, 0.f, 0.f};
#define STEPA(IDX, dtv_, hv_, Bv_, Cv_) {                  \
    float dtv = dtv_; float hvv = hv_;                     \
    float dA = fexp2(An2 * dt_prev);                       \
    g = dtv * (Bv_) * hvv + dA * g;                        \
    float p = g * (Cv_);                                   \
    ROWSUM16(p);                                           \
    if (n == ((IDX) & 15)) {                               \
      pcap[(IDX) >> 4] = p; hcap[(IDX) >> 4] = hvv;        \
    }                                                      \
    dt_prev = dtv; }
#pragma unroll
  for (int s = 7; s >= 0; --s) {
    uint4 d8 = *(const uint4*)(&dt_t[dl][s * 8]);
    uint4 h8 = *(const uint4*)(&hid_t[dl][s * 8]);
    f32x4 b0 = *(const f32x4*)(&B_t[n][s * 8]);
    f32x4 b1 = *(const f32x4*)(&B_t[n][s * 8 + 4]);
    f32x4 c0 = *(const f32x4*)(&C_t[n][s * 8]);
    f32x4 c1 = *(const f32x4*)(&C_t[n][s * 8 + 4]);
    STEPA(s * 8 + 7, B2F_HI(d8.w), B2F_HI(h8.w), b1[3], c1[3]);
    STEPA(s * 8 + 6, B2F_LO(d8.w), B2F_LO(h8.w), b1[2], c1[2]);
    STEPA(s * 8 + 5, B2F_HI(d8.z), B2F_HI(h8.z), b1[1], c1[1]);
    STEPA(s * 8 + 4, B2F_LO(d8.z), B2F_LO(h8.z), b1[0], c1[0]);
    STEPA(s * 8 + 3, B2F_HI(d8.y), B2F_HI(h8.y), b0[3], c0[3]);
    STEPA(s * 8 + 2, B2F_LO(d8.y), B2F_LO(h8.y), b0[2], c0[2]);
    STEPA(s * 8 + 1, B2F_HI(d8.x), B2F_HI(h8.x), b0[1], c0[1]);
    STEPA(s * 8 + 0, B2F_LO(d8.x), B2F_LO(h8.x), b0[0], c0[0]);
  }
#undef STEPA
#pragma unroll
  for (int j2 = 0; j2 < 4; ++j2) {
    float gv = b2f(gate_t[dl][n + 16 * j2]);
    float yv = (1.3f * pcap[j2] + hcap[j2] * Dd) * silu_f(gv);
    y_s[n + 16 * j2][dl] = f2b(yv);
  }
  __syncthreads();
  {
    int r = t >> 2, q = t & 3;
    *(uint2*)(y + ((size_t)bb * LSEQ + l0 + r) * DI + d0 + q * 4) =
        *(const uint2*)(&y_s[r][q * 4]);
  }
}

// ---------------- host ----------------
extern "C" void kernel_launch(void* const* d_in, const int* in_sizes, int n_in,
                              void* d_out, int out_size, void* d_ws, size_t ws_size,
                              hipStream_t stream) {
  const float* x_in   = (const float*)d_in[0];
  const float* w_in   = (const float*)d_in[1];
  const float* conv_w = (const float*)d_in[2];
  const float* conv_b = (const float*)d_in[3];
  const float* w_x    = (const float*)d_in[4];
  const float* w_dt   = (const float*)d_in[5];
  const float* b_dt   = (const float*)d_in[6];
  const float* A_log  = (const float*)d_in[7];
  const float* Dp     = (const float*)d_in[8];
  const float* w_out  = (const float*)d_in[9];
  float* outp = (float*)d_out;

  size_t off = 0;
  auto carve = [&](size_t bytes) {
    void* p = (char*)d_ws + off;
    off += (bytes + 255) & ~(size_t)255;
    return p;
  };
  u16*   in_b   = (u16*)  carve((size_t)NLB * DM * 2);
  u16*   win_b  = (u16*)  carve((size_t)E2 * DM * 2);
  u16*   wout_b = (u16*)  carve((size_t)DM * DI * 2);
  u16*   wx_b   = (u16*)  carve((size_t)SSMW * DI * 2);
  u16*   wdtp_b = (u16*)  carve((size_t)DI * 64 * 2);
  u16*   proj_b = (u16*)  carve((size_t)NB * E2 * LSEQ * 2);
  u16*   hid_b  = (u16*)  carve((size_t)NLB * DI * 2);
  float* ssm_b  = (float*)carve((size_t)NLB * SSMW * 4);
  u16*   dtin_b = (u16*)  carve((size_t)(NLB + 64) * 64 * 2);  // +64 rows OOB-read slack
  u16*   y_b    = (u16*)  carve((size_t)NLB * DI * 2);
  float* gsum_b = (float*)carve((size_t)NB * NC * DI * 16 * 4);
  float* sdt_b  = (float*)carve((size_t)NB * NC * DI * 16 * 4);
  float* car_b  = (float*)carve((size_t)NB * NC * DI * 16 * 4);

  const int ncast = NLB * DM + E2 * DM + DM * DI + SSMW * DI + DI * 64;
  castall<<<(ncast + 1023) / 1024, 256, 0, stream>>>(
      x_in, w_in, w_out, w_x, w_dt, b_dt, in_b, win_b, wout_b, wx_b, wdtp_b);

  gemm_bt<0><<<dim3(E2 / 128, NLB / 128), 256, 0, stream>>>(
      win_b, in_b, proj_b, E2, NLB, DM);
  conv_silu<<<dim3(DI / 64, LSEQ / 64, NB), 256, 0, stream>>>(
      proj_b, conv_w, conv_b, hid_b);
  gemm_xproj<<<NLB / 128, 256, 0, stream>>>(wx_b, hid_b, ssm_b, dtin_b);

  scan_sum<<<dim3(DI / 16, NC, NB), 256, 0, stream>>>(
      dtin_b, wdtp_b, hid_b, ssm_b, A_log, gsum_b, sdt_b);
  scan_carry<<<dim3(DI * 16 / 256, NB), 256, 0, stream>>>(
      gsum_b, sdt_b, A_log, car_b);
  scan_apply<<<dim3(DI / 16, NC, NB), 256, 0, stream>>>(
      proj_b, hid_b, dtin_b, wdtp_b, ssm_b, A_log, Dp, car_b, y_b);

  gemm_bt<1><<<dim3(NLB / 128, DM / 128), 256, 0, stream>>>(
      y_b, wout_b, outp, NLB, DM, DI);
}

// Round 12
// 285.918 us; speedup vs baseline: 1.1991x; 1.0422x over previous
//
#include <hip/hip_runtime.h>
#include <hip/hip_bf16.h>

#define DI     1536
#define DM     768
#define E2     3072
#define NST    16
#define LSEQ   2048
#define NB     2
#define NLB    4096
#define SSMW   80
#define DTRANK 48
#define NC     32     // scan chunks
#define CP     64     // chunk length = LSEQ/NC
#define LOG2E  1.44269504f
#define RLOG2E 0.69314718f

typedef unsigned short u16;
typedef unsigned int   u32;
typedef __attribute__((ext_vector_type(8))) __bf16 bf16x8;
typedef __attribute__((ext_vector_type(4))) float  f32x4;

__device__ __forceinline__ float b2f(u16 u) {
  union { u32 i; float f; } v; v.i = ((u32)u) << 16; return v.f;
}
__device__ __forceinline__ u16 f2b(float f) {
  union { float f; u32 i; } v; v.f = f;
  u32 r = v.i + 0x7FFFu + ((v.i >> 16) & 1u);
  return (u16)(r >> 16);
}
__device__ __forceinline__ void gld16(const u16* g, u16* l) {
  __builtin_amdgcn_global_load_lds(
      (const __attribute__((address_space(1))) void*)g,
      (__attribute__((address_space(3))) void*)l, 16, 0, 0);
}
__device__ __forceinline__ float silu_f(float x) {
  return x / (1.f + __expf(-x));
}
// raw v_exp_f32 / v_log_f32 (no OCML denormal fixup; round-8 lesson)
__device__ __forceinline__ float fexp2(float x) { return __builtin_amdgcn_exp2f(x); }
__device__ __forceinline__ float flog2(float x) { return __builtin_amdgcn_logf(x); }
// softplus = log2(1 + 2^(x*log2e)) / log2e ; guard keeps large x exact
__device__ __forceinline__ float softplus_f(float x) {
  return (x > 20.f) ? x : flog2(1.f + fexp2(x * LOG2E)) * RLOG2E;
}

// full 16-lane-row sum via DPP rotations, tied operands (no copy insertion).
#define ROWSUM16(p)                                                                \
  asm("v_add_f32 %0, %0, %0 row_ror:8 row_mask:0xf bank_mask:0xf" : "+v"(p));      \
  asm("v_add_f32 %0, %0, %0 row_ror:4 row_mask:0xf bank_mask:0xf" : "+v"(p));      \
  asm("v_add_f32 %0, %0, %0 row_ror:2 row_mask:0xf bank_mask:0xf" : "+v"(p));      \
  asm("v_add_f32 %0, %0, %0 row_ror:1 row_mask:0xf bank_mask:0xf" : "+v"(p));

// ---- fused cast f32 -> bf16: x_in, w_in, w_out, w_x, and wdt-pad (col48=b_dt) ----
__global__ __launch_bounds__(256) void castall(const float* __restrict__ x_in,
                                               const float* __restrict__ w_in,
                                               const float* __restrict__ w_out,
                                               const float* __restrict__ w_x,
                                               const float* __restrict__ w_dt,
                                               const float* __restrict__ b_dt,
                                               u16* __restrict__ in_b,
                                               u16* __restrict__ win_b,
                                               u16* __restrict__ wout_b,
                                               u16* __restrict__ wx_b,
                                               u16* __restrict__ wdtp_b) {
  int i = (blockIdx.x * 256 + threadIdx.x) * 4;
  const int n1 = NLB * DM, n2 = n1 + E2 * DM, n3 = n2 + DM * DI, n4 = n3 + SSMW * DI;
  const int n5 = n4 + DI * 64;
  if (i >= n5) return;
  if (i >= n4) {
    int off = i - n4;
    u16 o[4];
#pragma unroll
    for (int j = 0; j < 4; j++) {
      int row = (off + j) >> 6, col = (off + j) & 63;
      float v = (col < 48) ? w_dt[row * 48 + col] : (col == 48 ? b_dt[row] : 0.f);
      o[j] = f2b(v);
    }
    uint2 pk; pk.x = (u32)o[0] | ((u32)o[1] << 16); pk.y = (u32)o[2] | ((u32)o[3] << 16);
    *(uint2*)(wdtp_b + off) = pk;
    return;
  }
  const float* src; u16* dst; int off;
  if (i < n1)      { src = x_in;  dst = in_b;   off = i; }
  else if (i < n2) { src = w_in;  dst = win_b;  off = i - n1; }
  else if (i < n3) { src = w_out; dst = wout_b; off = i - n2; }
  else             { src = w_x;   dst = wx_b;   off = i - n3; }
  float4 v = *(const float4*)(src + off);
  u32 lo = (u32)f2b(v.x) | ((u32)f2b(v.y) << 16);
  u32 hi = (u32)f2b(v.z) | ((u32)f2b(v.w) << 16);
  uint2 pk; pk.x = lo; pk.y = hi;
  *(uint2*)(dst + off) = pk;
}

// ---------------- 128x128 BT GEMM, BK=32, bf16 MFMA ----------------
// CMODE 0: bf16 out, proj layout.  CMODE 1: f32 out, row-major m*N+n.
template<int CMODE>
__global__ __launch_bounds__(256) void gemm_bt(const u16* __restrict__ A,
                                               const u16* __restrict__ B,
                                               void* __restrict__ Cp,
                                               int M, int N, int K) {
  __shared__ __align__(16) u16 a_s[128 * 32];
  __shared__ __align__(16) u16 b_s[128 * 32];
  const int tid = threadIdx.x, lane = tid & 63, w = tid >> 6;
  const int m0 = blockIdx.x * 128, n0 = blockIdx.y * 128;
  const int wm = w >> 1, wn = w & 1;
  f32x4 acc[4][4];
#pragma unroll
  for (int i = 0; i < 4; i++)
#pragma unroll
    for (int j = 0; j < 4; j++) acc[i][j] = (f32x4){0.f, 0.f, 0.f, 0.f};

  const int rA = lane >> 2;
  const int c8 = (lane & 3) * 8;
  const int fr = lane & 15;
  const int fk = (lane >> 4) * 8;

  for (int k0 = 0; k0 < K; k0 += 32) {
#pragma unroll
    for (int j = 0; j < 2; j++) {
      int rr = (w * 2 + j) * 16;
      gld16(A + (size_t)(m0 + rr + rA) * K + k0 + c8, a_s + rr * 32);
      gld16(B + (size_t)(n0 + rr + rA) * K + k0 + c8, b_s + rr * 32);
    }
    __syncthreads();
    bf16x8 af[4], bf[4];
#pragma unroll
    for (int mi = 0; mi < 4; mi++)
      af[mi] = *(const bf16x8*)(a_s + (wm * 64 + mi * 16 + fr) * 32 + fk);
#pragma unroll
    for (int ni = 0; ni < 4; ni++)
      bf[ni] = *(const bf16x8*)(b_s + (wn * 64 + ni * 16 + fr) * 32 + fk);
#pragma unroll
    for (int mi = 0; mi < 4; mi++)
#pragma unroll
      for (int ni = 0; ni < 4; ni++)
        acc[mi][ni] = __builtin_amdgcn_mfma_f32_16x16x32_bf16(
            af[mi], bf[ni], acc[mi][ni], 0, 0, 0);
    __syncthreads();
  }

  const int rbase = (lane >> 4) * 4, cbase = lane & 15;
#pragma unroll
  for (int mi = 0; mi < 4; mi++)
#pragma unroll
    for (int ni = 0; ni < 4; ni++)
#pragma unroll
      for (int j = 0; j < 4; j++) {
        int m = m0 + wm * 64 + mi * 16 + rbase + j;
        int n = n0 + wn * 64 + ni * 16 + cbase;
        float v = acc[mi][ni][j];
        if (CMODE == 0) {
          u16* C = (u16*)Cp;
          C[((size_t)(n >> 11) * E2 + m) * LSEQ + (n & 2047)] = f2b(v);
        } else {
          float* C = (float*)Cp;
          C[(size_t)m * N + n] = v;
        }
      }
}

// ---------------- x_proj GEMM: M=80 (staged 128), N-tile 128 ----------------
// Also emits dt-rank rows (m<48) as bf16 into dtin [n][64]; col48=1.0 (bias), 49..63=0.
__global__ __launch_bounds__(256) void gemm_xproj(const u16* __restrict__ A,
                                                  const u16* __restrict__ B,
                                                  float* __restrict__ C,
                                                  u16* __restrict__ dtin) {
  __shared__ __align__(16) u16 a_s[128 * 32];
  __shared__ __align__(16) u16 b_s[128 * 32];
  const int tid = threadIdx.x, lane = tid & 63, w = tid >> 6;
  const int n0 = blockIdx.x * 128;
  const int K = DI;
  f32x4 acc[5][2];
#pragma unroll
  for (int i = 0; i < 5; i++) { acc[i][0] = (f32x4){0,0,0,0}; acc[i][1] = (f32x4){0,0,0,0}; }

  const int rA = lane >> 2;
  const int c8 = (lane & 3) * 8;
  const int fr = lane & 15;
  const int fk = (lane >> 4) * 8;

  for (int k0 = 0; k0 < K; k0 += 32) {
#pragma unroll
    for (int j = 0; j < 2; j++) {
      int rr = (w * 2 + j) * 16;
      gld16(A + (size_t)(rr + rA) * K + k0 + c8, a_s + rr * 32);
      gld16(B + (size_t)(n0 + rr + rA) * K + k0 + c8, b_s + rr * 32);
    }
    __syncthreads();
    bf16x8 af[5], bf[2];
#pragma unroll
    for (int mi = 0; mi < 5; mi++)
      af[mi] = *(const bf16x8*)(a_s + (mi * 16 + fr) * 32 + fk);
#pragma unroll
    for (int ni = 0; ni < 2; ni++)
      bf[ni] = *(const bf16x8*)(b_s + (w * 32 + ni * 16 + fr) * 32 + fk);
#pragma unroll
    for (int mi = 0; mi < 5; mi++)
#pragma unroll
      for (int ni = 0; ni < 2; ni++)
        acc[mi][ni] = __builtin_amdgcn_mfma_f32_16x16x32_bf16(
            af[mi], bf[ni], acc[mi][ni], 0, 0, 0);
    __syncthreads();
  }

  const int rbase = (lane >> 4) * 4, cbase = lane & 15;
#pragma unroll
  for (int mi = 0; mi < 5; mi++)
#pragma unroll
    for (int ni = 0; ni < 2; ni++)
#pragma unroll
      for (int j = 0; j < 4; j++) {
        int m = mi * 16 + rbase + j;
        int n = n0 + w * 32 + ni * 16 + cbase;
        float v = acc[mi][ni][j];
        C[(size_t)n * SSMW + m] = v;
        if (m < 64) {
          u16 dv = (m < 48) ? f2b(v) : (m == 48 ? f2b(1.0f) : (u16)0);
          dtin[(size_t)n * 64 + m] = dv;
        }
      }
}

// ---------------- causal depthwise conv(4) + SiLU ----------------
__global__ __launch_bounds__(256) void conv_silu(const u16* __restrict__ proj,
                                                 const float* __restrict__ cw,
                                                 const float* __restrict__ cb,
                                                 u16* __restrict__ hidden) {
  __shared__ __align__(16) u16 in_s[64][96];
  __shared__ __align__(16) u16 o_s[64][64];
  const int t = threadIdx.x;
  const int d0 = blockIdx.x * 64, l0 = blockIdx.y * 64, bb = blockIdx.z;

  for (int c = t; c < 64 * 12; c += 256) {
    int r = c / 12, q = c % 12;
    int gl = l0 - 32 + q * 8;
    uint4 v;
    if (gl >= 0) v = *(const uint4*)(proj + ((size_t)bb * E2 + d0 + r) * LSEQ + gl);
    else         v = (uint4){0u, 0u, 0u, 0u};
    *(uint4*)(&in_s[r][q * 8]) = v;
  }
  __syncthreads();

  const int dd = t >> 2, ls = t & 3;
  const int d = d0 + dd;
  const float w0 = cw[d * 4 + 0], w1 = cw[d * 4 + 1], w2 = cw[d * 4 + 2], w3 = cw[d * 4 + 3];
  const float bias = cb[d];
#pragma unroll
  for (int i = 0; i < 16; i++) {
    int li = ls * 16 + i;
    int base = 32 + li - 3;
    float h = w0 * b2f(in_s[dd][base + 0]) + w1 * b2f(in_s[dd][base + 1]) +
              w2 * b2f(in_s[dd][base + 2]) + w3 * b2f(in_s[dd][base + 3]) + bias;
    o_s[li][dd] = f2b(silu_f(h));
  }
  __syncthreads();

  for (int c = t; c < 512; c += 256) {
    int r = c >> 3, q = c & 7;
    *(uint4*)(hidden + ((size_t)bb * LSEQ + l0 + r) * DI + d0 + q * 8) =
        *(const uint4*)(&o_s[r][q * 8]);
  }
}

// ================= chunked parallel suffix scan, dt fused via MFMA, f32 LDS =================
// dt tile [l0..l0+79][d0..d0+15] = softplus(dtin(K=64) . wdtp^T), stored f32.
// dt_f rows are 84 wide: the MFMA writes cols 0..79 (5 m-tiles x 16); 68 was OOB (caught r11 audit).

#define DT_TILE_MFMA(dtin, wdtp)                                                          \
  {                                                                                       \
    const u16* ar = dtin + ((size_t)bb * LSEQ + l0) * 64;                                 \
    bf16x8 wb0 = *(const bf16x8*)(wdtp + (size_t)(d0 + fr) * 64 + fk);                    \
    bf16x8 wb1 = *(const bf16x8*)(wdtp + (size_t)(d0 + fr) * 64 + 32 + fk);               \
    for (int mt = wv; mt < 5; mt += 4) {                                                  \
      bf16x8 a0 = *(const bf16x8*)(ar + (size_t)(mt * 16 + fr) * 64 + fk);                \
      bf16x8 a1 = *(const bf16x8*)(ar + (size_t)(mt * 16 + fr) * 64 + 32 + fk);           \
      f32x4 da = (f32x4){0.f, 0.f, 0.f, 0.f};                                             \
      da = __builtin_amdgcn_mfma_f32_16x16x32_bf16(a0, wb0, da, 0, 0, 0);                 \
      da = __builtin_amdgcn_mfma_f32_16x16x32_bf16(a1, wb1, da, 0, 0, 0);                 \
      _Pragma("unroll")                                                                   \
      for (int j = 0; j < 4; j++)                                                         \
        dt_f[cbase][mt * 16 + rbase + j] = softplus_f(da[j]);                             \
    }                                                                                     \
  }

// Phase A: per-chunk local summary -> gsum (g_local at l0), sdt (sum dt over (l0,l1])
__global__ __launch_bounds__(256) void scan_sum(const u16* __restrict__ dtin,
                                                const u16* __restrict__ wdtp,
                                                const u16* __restrict__ hidden,
                                                const float* __restrict__ ssm,
                                                const float* __restrict__ A_log,
                                                float* __restrict__ gsum,
                                                float* __restrict__ sdt) {
  __shared__ __align__(16) float dt_f[16][84];
  __shared__ __align__(16) float hid_f[16][68];
  __shared__ __align__(16) float B_t[16][68];
  const int t = threadIdx.x;
  const int d0 = blockIdx.x * 16, c = blockIdx.y, bb = blockIdx.z;
  const int dl = t >> 4, n = t & 15;
  const int d = d0 + dl;
  const int l0 = c * CP;
  const int lane = t & 63, wv = t >> 6;
  const int fr = lane & 15, fk = (lane >> 4) * 8;
  const int rbase = (lane >> 4) * 4, cbase = lane & 15;
  {
    int r = t >> 2, q = t & 3;
    size_t lbrow = (size_t)bb * LSEQ + l0 + r;
    uint2 hv = *(const uint2*)(hidden + lbrow * DI + d0 + q * 4);
    float4 bv = *(const float4*)(ssm + lbrow * SSMW + 48 + q * 4);
    hid_f[q * 4 + 0][r] = b2f((u16)hv.x); hid_f[q * 4 + 1][r] = b2f((u16)(hv.x >> 16));
    hid_f[q * 4 + 2][r] = b2f((u16)hv.y); hid_f[q * 4 + 3][r] = b2f((u16)(hv.y >> 16));
    B_t[q * 4 + 0][r] = bv.x; B_t[q * 4 + 1][r] = bv.y;
    B_t[q * 4 + 2][r] = bv.z; B_t[q * 4 + 3][r] = bv.w;
  }
  DT_TILE_MFMA(dtin, wdtp)
  const float An2 = -__expf(A_log[d * 16 + n]) * LOG2E;
  __syncthreads();
  float dt_prev = (c == NC - 1) ? 0.f : dt_f[dl][64];
  float g = 0.f, sumdt = 0.f;
#define STEPS(dtv_, hv_, Bv_) {            \
    float dtv = dtv_;                      \
    float dA = fexp2(An2 * dt_prev);       \
    g = dtv * (Bv_) * (hv_) + dA * g;      \
    sumdt += dt_prev;                      \
    dt_prev = dtv; }
#pragma unroll
  for (int s = 7; s >= 0; --s) {
    f32x4 t0 = *(const f32x4*)(&dt_f[dl][s * 8]);
    f32x4 t1 = *(const f32x4*)(&dt_f[dl][s * 8 + 4]);
    f32x4 h0 = *(const f32x4*)(&hid_f[dl][s * 8]);
    f32x4 h1 = *(const f32x4*)(&hid_f[dl][s * 8 + 4]);
    f32x4 b0 = *(const f32x4*)(&B_t[n][s * 8]);
    f32x4 b1 = *(const f32x4*)(&B_t[n][s * 8 + 4]);
    STEPS(t1[3], h1[3], b1[3]);
    STEPS(t1[2], h1[2], b1[2]);
    STEPS(t1[1], h1[1], b1[1]);
    STEPS(t1[0], h1[0], b1[0]);
    STEPS(t0[3], h0[3], b0[3]);
    STEPS(t0[2], h0[2], b0[2]);
    STEPS(t0[1], h0[1], b0[1]);
    STEPS(t0[0], h0[0], b0[0]);
  }
#undef STEPS
  size_t idx = (((size_t)bb * NC + c) * DI + d) * 16 + n;
  gsum[idx] = g;
  sdt[idx]  = sumdt;
}

// Phase B: serial combine over 32 chunk summaries -> carry[c]
__global__ __launch_bounds__(256) void scan_carry(const float* __restrict__ gsum,
                                                  const float* __restrict__ sdt,
                                                  const float* __restrict__ A_log,
                                                  float* __restrict__ carry) {
  const int t = blockIdx.x * 256 + threadIdx.x;
  const int bb = blockIdx.y;
  const int d = t >> 4, n = t & 15;
  const float An2 = -__expf(A_log[d * 16 + n]) * LOG2E;
  float cg = 0.f;
  carry[(((size_t)bb * NC + NC - 1) * DI + d) * 16 + n] = 0.f;
  for (int c = NC - 2; c >= 0; --c) {
    size_t up = (((size_t)bb * NC + (c + 1)) * DI + d) * 16 + n;
    cg = gsum[up] + fexp2(An2 * sdt[up]) * cg;
    carry[(((size_t)bb * NC + c) * DI + d) * 16 + n] = cg;
  }
}

// Phase C: re-run local scan seeded with carry; fuse C-proj, D, gating -> y
__global__ __launch_bounds__(256) void scan_apply(const u16* __restrict__ proj,
                                                  const u16* __restrict__ hidden,
                                                  const u16* __restrict__ dtin,
                                                  const u16* __restrict__ wdtp,
                                                  const float* __restrict__ ssm,
                                                  const float* __restrict__ A_log,
                                                  const float* __restrict__ Dp,
                                                  const float* __restrict__ carry,
                                                  u16* __restrict__ y) {
  __shared__ __align__(16) float dt_f[16][84];
  __shared__ __align__(16) float hid_f[16][68];
  __shared__ __align__(16) float B_t[16][68];
  __shared__ __align__(16) float C_t[16][68];
  __shared__ __align__(16) u16 gate_t[16][80];
  __shared__ __align__(16) u16 y_s[64][16];
  const int t = threadIdx.x;
  const int d0 = blockIdx.x * 16, c = blockIdx.y, bb = blockIdx.z;
  const int dl = t >> 4, n = t & 15;
  const int d = d0 + dl;
  const int l0 = c * CP;
  const int lane = t & 63, wv = t >> 6;
  const int fr = lane & 15, fk = (lane >> 4) * 8;
  const int rbase = (lane >> 4) * 4, cbase = lane & 15;
  {
    int r = t >> 2, q = t & 3;
    size_t lbrow = (size_t)bb * LSEQ + l0 + r;
    uint2 hv = *(const uint2*)(hidden + lbrow * DI + d0 + q * 4);
    float4 bv = *(const float4*)(ssm + lbrow * SSMW + 48 + q * 4);
    float4 cv = *(const float4*)(ssm + lbrow * SSMW + 64 + q * 4);
    hid_f[q * 4 + 0][r] = b2f((u16)hv.x); hid_f[q * 4 + 1][r] = b2f((u16)(hv.x >> 16));
    hid_f[q * 4 + 2][r] = b2f((u16)hv.y); hid_f[q * 4 + 3][r] = b2f((u16)(hv.y >> 16));
    B_t[q * 4 + 0][r] = bv.x; B_t[q * 4 + 1][r] = bv.y;
    B_t[q * 4 + 2][r] = bv.z; B_t[q * 4 + 3][r] = bv.w;
    C_t[q * 4 + 0][r] = cv.x; C_t[q * 4 + 1][r] = cv.y;
    C_t[q * 4 + 2][r] = cv.z; C_t[q * 4 + 3][r] = cv.w;
  }
  {
    int r = t >> 4, q = t & 15;
    *(uint2*)(&gate_t[r][q * 4]) =
        *(const uint2*)(proj + ((size_t)bb * E2 + DI + d0 + r) * LSEQ + l0 + q * 4);
  }
  DT_TILE_MFMA(dtin, wdtp)
  const float An2 = -__expf(A_log[d * 16 + n]) * LOG2E;
  const float Dd = Dp[d];
  float g = carry[(((size_t)bb * NC + c) * DI + d) * 16 + n];
  __syncthreads();
  float dt_prev = (c == NC - 1) ? 0.f : dt_f[dl][64];
  float pcap[4] = {0.f, 0.f, 0.f, 0.f};
#define STEPA(IDX, dtv_, hv_, Bv_, Cv_) {                  \
    float dtv = dtv_;                                      \
    float dA = fexp2(An2 * dt_prev);                       \
    g = dtv * (Bv_) * (hv_) + dA * g;                      \
    float p = g * (Cv_);                                   \
    ROWSUM16(p);                                           \
    if (n == ((IDX) & 15)) pcap[(IDX) >> 4] = p;           \
    dt_prev = dtv; }
#pragma unroll
  for (int s = 7; s >= 0; --s) {
    f32x4 t0 = *(const f32x4*)(&dt_f[dl][s * 8]);
    f32x4 t1 = *(const f32x4*)(&dt_f[dl][s * 8 + 4]);
    f32x4 h0 = *(const f32x4*)(&hid_f[dl][s * 8]);
    f32x4 h1 = *(const f32x4*)(&hid_f[dl][s * 8 + 4]);
    f32x4 b0 = *(const f32x4*)(&B_t[n][s * 8]);
    f32x4 b1 = *(const f32x4*)(&B_t[n][s * 8 + 4]);
    f32x4 c0 = *(const f32x4*)(&C_t[n][s * 8]);
    f32x4 c1 = *(const f32x4*)(&C_t[n][s * 8 + 4]);
    STEPA(s * 8 + 7, t1[3], h1[3], b1[3], c1[3]);
    STEPA(s * 8 + 6, t1[2], h1[2], b1[2], c1[2]);
    STEPA(s * 8 + 5, t1[1], h1[1], b1[1], c1[1]);
    STEPA(s * 8 + 4, t1[0], h1[0], b1[0], c1[0]);
    STEPA(s * 8 + 3, t0[3], h0[3], b0[3], c0[3]);
    STEPA(s * 8 + 2, t0[2], h0[2], b0[2], c0[2]);
    STEPA(s * 8 + 1, t0[1], h0[1], b0[1], c0[1]);
    STEPA(s * 8 + 0, t0[0], h0[0], b0[0], c0[0]);
  }
#undef STEPA
#pragma unroll
  for (int j2 = 0; j2 < 4; ++j2) {
    float hval = hid_f[dl][n + 16 * j2];
    float gv = b2f(gate_t[dl][n + 16 * j2]);
    float yv = (1.3f * pcap[j2] + hval * Dd) * silu_f(gv);
    y_s[n + 16 * j2][dl] = f2b(yv);
  }
  __syncthreads();
  {
    int r = t >> 2, q = t & 3;
    *(uint2*)(y + ((size_t)bb * LSEQ + l0 + r) * DI + d0 + q * 4) =
        *(const uint2*)(&y_s[r][q * 4]);
  }
}

// ---------------- host ----------------
extern "C" void kernel_launch(void* const* d_in, const int* in_sizes, int n_in,
                              void* d_out, int out_size, void* d_ws, size_t ws_size,
                              hipStream_t stream) {
  const float* x_in   = (const float*)d_in[0];
  const float* w_in   = (const float*)d_in[1];
  const float* conv_w = (const float*)d_in[2];
  const float* conv_b = (const float*)d_in[3];
  const float* w_x    = (const float*)d_in[4];
  const float* w_dt   = (const float*)d_in[5];
  const float* b_dt   = (const float*)d_in[6];
  const float* A_log  = (const float*)d_in[7];
  const float* Dp     = (const float*)d_in[8];
  const float* w_out  = (const float*)d_in[9];
  float* outp = (float*)d_out;

  size_t off = 0;
  auto carve = [&](size_t bytes) {
    void* p = (char*)d_ws + off;
    off += (bytes + 255) & ~(size_t)255;
    return p;
  };
  u16*   in_b   = (u16*)  carve((size_t)NLB * DM * 2);
  u16*   win_b  = (u16*)  carve((size_t)E2 * DM * 2);
  u16*   wout_b = (u16*)  carve((size_t)DM * DI * 2);
  u16*   wx_b   = (u16*)  carve((size_t)SSMW * DI * 2);
  u16*   wdtp_b = (u16*)  carve((size_t)DI * 64 * 2);
  u16*   proj_b = (u16*)  carve((size_t)NB * E2 * LSEQ * 2);
  u16*   hid_b  = (u16*)  carve((size_t)NLB * DI * 2);
  float* ssm_b  = (float*)carve((size_t)NLB * SSMW * 4);
  u16*   dtin_b = (u16*)  carve((size_t)(NLB + 64) * 64 * 2);  // +64 rows OOB-read slack
  u16*   y_b    = (u16*)  carve((size_t)NLB * DI * 2);
  float* gsum_b = (float*)carve((size_t)NB * NC * DI * 16 * 4);
  float* sdt_b  = (float*)carve((size_t)NB * NC * DI * 16 * 4);
  float* car_b  = (float*)carve((size_t)NB * NC * DI * 16 * 4);

  const int ncast = NLB * DM + E2 * DM + DM * DI + SSMW * DI + DI * 64;
  castall<<<(ncast + 1023) / 1024, 256, 0, stream>>>(
      x_in, w_in, w_out, w_x, w_dt, b_dt, in_b, win_b, wout_b, wx_b, wdtp_b);

  gemm_bt<0><<<dim3(E2 / 128, NLB / 128), 256, 0, stream>>>(
      win_b, in_b, proj_b, E2, NLB, DM);
  conv_silu<<<dim3(DI / 64, LSEQ / 64, NB), 256, 0, stream>>>(
      proj_b, conv_w, conv_b, hid_b);
  gemm_xproj<<<NLB / 128, 256, 0, stream>>>(wx_b, hid_b, ssm_b, dtin_b);

  scan_sum<<<dim3(DI / 16, NC, NB), 256, 0, stream>>>(
      dtin_b, wdtp_b, hid_b, ssm_b, A_log, gsum_b, sdt_b);
  scan_carry<<<dim3(DI * 16 / 256, NB), 256, 0, stream>>>(
      gsum_b, sdt_b, A_log, car_b);
  scan_apply<<<dim3(DI / 16, NC, NB), 256, 0, stream>>>(
      proj_b, hid_b, dtin_b, wdtp_b, ssm_b, A_log, Dp, car_b, y_b);

  gemm_bt<1><<<dim3(NLB / 128, DM / 128), 256, 0, stream>>>(
      y_b, wout_b, outp, NLB, DM, DI);
}

// Round 13
// 284.654 us; speedup vs baseline: 1.2044x; 1.0044x over previous
//
#include <hip/hip_runtime.h>
#include <hip/hip_bf16.h>

#define DI     1536
#define DM     768
#define E2     3072
#define NST    16
#define LSEQ   2048
#define NB     2
#define NLB    4096
#define SSMW   80
#define DTRANK 48
#define NC     32     // scan chunks
#define CP     64     // chunk length = LSEQ/NC
#define LOG2E  1.44269504f
#define RLOG2E 0.69314718f

typedef unsigned short u16;
typedef unsigned int   u32;
typedef __attribute__((ext_vector_type(8))) __bf16 bf16x8;
typedef __attribute__((ext_vector_type(4))) float  f32x4;

__device__ __forceinline__ float b2f(u16 u) {
  union { u32 i; float f; } v; v.i = ((u32)u) << 16; return v.f;
}
__device__ __forceinline__ u16 f2b(float f) {
  union { float f; u32 i; } v; v.f = f;
  u32 r = v.i + 0x7FFFu + ((v.i >> 16) & 1u);
  return (u16)(r >> 16);
}
__device__ __forceinline__ void gld16(const u16* g, u16* l) {
  __builtin_amdgcn_global_load_lds(
      (const __attribute__((address_space(1))) void*)g,
      (__attribute__((address_space(3))) void*)l, 16, 0, 0);
}
__device__ __forceinline__ float silu_f(float x) {
  return x / (1.f + __expf(-x));
}
// raw v_exp_f32 / v_log_f32 (no OCML denormal fixup; round-8 lesson)
__device__ __forceinline__ float fexp2(float x) { return __builtin_amdgcn_exp2f(x); }
__device__ __forceinline__ float flog2(float x) { return __builtin_amdgcn_logf(x); }
// softplus = log2(1 + 2^(x*log2e)) / log2e ; guard keeps large x exact
__device__ __forceinline__ float softplus_f(float x) {
  return (x > 20.f) ? x : flog2(1.f + fexp2(x * LOG2E)) * RLOG2E;
}

// full 16-lane-row sum via DPP rotations, tied operands (no copy insertion).
#define ROWSUM16(p)                                                                \
  asm("v_add_f32 %0, %0, %0 row_ror:8 row_mask:0xf bank_mask:0xf" : "+v"(p));      \
  asm("v_add_f32 %0, %0, %0 row_ror:4 row_mask:0xf bank_mask:0xf" : "+v"(p));      \
  asm("v_add_f32 %0, %0, %0 row_ror:2 row_mask:0xf bank_mask:0xf" : "+v"(p));      \
  asm("v_add_f32 %0, %0, %0 row_ror:1 row_mask:0xf bank_mask:0xf" : "+v"(p));

// ---- fused cast f32 -> bf16: x_in, w_in, w_out, w_x, and wdt-pad (col48=b_dt) ----
__global__ __launch_bounds__(256) void castall(const float* __restrict__ x_in,
                                               const float* __restrict__ w_in,
                                               const float* __restrict__ w_out,
                                               const float* __restrict__ w_x,
                                               const float* __restrict__ w_dt,
                                               const float* __restrict__ b_dt,
                                               u16* __restrict__ in_b,
                                               u16* __restrict__ win_b,
                                               u16* __restrict__ wout_b,
                                               u16* __restrict__ wx_b,
                                               u16* __restrict__ wdtp_b) {
  int i = (blockIdx.x * 256 + threadIdx.x) * 4;
  const int n1 = NLB * DM, n2 = n1 + E2 * DM, n3 = n2 + DM * DI, n4 = n3 + SSMW * DI;
  const int n5 = n4 + DI * 64;
  if (i >= n5) return;
  if (i >= n4) {
    int off = i - n4;
    u16 o[4];
#pragma unroll
    for (int j = 0; j < 4; j++) {
      int row = (off + j) >> 6, col = (off + j) & 63;
      float v = (col < 48) ? w_dt[row * 48 + col] : (col == 48 ? b_dt[row] : 0.f);
      o[j] = f2b(v);
    }
    uint2 pk; pk.x = (u32)o[0] | ((u32)o[1] << 16); pk.y = (u32)o[2] | ((u32)o[3] << 16);
    *(uint2*)(wdtp_b + off) = pk;
    return;
  }
  const float* src; u16* dst; int off;
  if (i < n1)      { src = x_in;  dst = in_b;   off = i; }
  else if (i < n2) { src = w_in;  dst = win_b;  off = i - n1; }
  else if (i < n3) { src = w_out; dst = wout_b; off = i - n2; }
  else             { src = w_x;   dst = wx_b;   off = i - n3; }
  float4 v = *(const float4*)(src + off);
  u32 lo = (u32)f2b(v.x) | ((u32)f2b(v.y) << 16);
  u32 hi = (u32)f2b(v.z) | ((u32)f2b(v.w) << 16);
  uint2 pk; pk.x = lo; pk.y = hi;
  *(uint2*)(dst + off) = pk;
}

// ---------------- 128x128 BT GEMM, BK=32, bf16 MFMA, XCD-swizzled ----------------
// CMODE 0: bf16 out, proj layout.  CMODE 1: f32 out, row-major m*N+n.
// Grid x*y must be divisible by 8 (both call sites: 768, 192).
template<int CMODE>
__global__ __launch_bounds__(256) void gemm_bt(const u16* __restrict__ A,
                                               const u16* __restrict__ B,
                                               void* __restrict__ Cp,
                                               int M, int N, int K) {
  __shared__ __align__(16) u16 a_s[128 * 32];
  __shared__ __align__(16) u16 b_s[128 * 32];
  const int tid = threadIdx.x, lane = tid & 63, w = tid >> 6;
  // XCD swizzle: orig%8 = XCD (round-robin dispatch); give each XCD a contiguous tile range.
  const int orig = blockIdx.y * gridDim.x + blockIdx.x;
  const int cpx = (gridDim.x * gridDim.y) >> 3;
  const int wgid = (orig & 7) * cpx + (orig >> 3);
  const int m0 = (wgid % gridDim.x) * 128, n0 = (wgid / gridDim.x) * 128;
  const int wm = w >> 1, wn = w & 1;
  f32x4 acc[4][4];
#pragma unroll
  for (int i = 0; i < 4; i++)
#pragma unroll
    for (int j = 0; j < 4; j++) acc[i][j] = (f32x4){0.f, 0.f, 0.f, 0.f};

  const int rA = lane >> 2;
  const int c8 = (lane & 3) * 8;
  const int fr = lane & 15;
  const int fk = (lane >> 4) * 8;

  for (int k0 = 0; k0 < K; k0 += 32) {
#pragma unroll
    for (int j = 0; j < 2; j++) {
      int rr = (w * 2 + j) * 16;
      gld16(A + (size_t)(m0 + rr + rA) * K + k0 + c8, a_s + rr * 32);
      gld16(B + (size_t)(n0 + rr + rA) * K + k0 + c8, b_s + rr * 32);
    }
    __syncthreads();
    bf16x8 af[4], bf[4];
#pragma unroll
    for (int mi = 0; mi < 4; mi++)
      af[mi] = *(const bf16x8*)(a_s + (wm * 64 + mi * 16 + fr) * 32 + fk);
#pragma unroll
    for (int ni = 0; ni < 4; ni++)
      bf[ni] = *(const bf16x8*)(b_s + (wn * 64 + ni * 16 + fr) * 32 + fk);
#pragma unroll
    for (int mi = 0; mi < 4; mi++)
#pragma unroll
      for (int ni = 0; ni < 4; ni++)
        acc[mi][ni] = __builtin_amdgcn_mfma_f32_16x16x32_bf16(
            af[mi], bf[ni], acc[mi][ni], 0, 0, 0);
    __syncthreads();
  }

  const int rbase = (lane >> 4) * 4, cbase = lane & 15;
#pragma unroll
  for (int mi = 0; mi < 4; mi++)
#pragma unroll
    for (int ni = 0; ni < 4; ni++)
#pragma unroll
      for (int j = 0; j < 4; j++) {
        int m = m0 + wm * 64 + mi * 16 + rbase + j;
        int n = n0 + wn * 64 + ni * 16 + cbase;
        float v = acc[mi][ni][j];
        if (CMODE == 0) {
          u16* C = (u16*)Cp;
          C[((size_t)(n >> 11) * E2 + m) * LSEQ + (n & 2047)] = f2b(v);
        } else {
          float* C = (float*)Cp;
          C[(size_t)m * N + n] = v;
        }
      }
}

// ---------------- x_proj GEMM: M=80 (staged 128), N-tile 128 ----------------
// Also emits dt-rank rows (m<48) as bf16 into dtin [n][64]; col48=1.0 (bias), 49..63=0.
__global__ __launch_bounds__(256) void gemm_xproj(const u16* __restrict__ A,
                                                  const u16* __restrict__ B,
                                                  float* __restrict__ C,
                                                  u16* __restrict__ dtin) {
  __shared__ __align__(16) u16 a_s[128 * 32];
  __shared__ __align__(16) u16 b_s[128 * 32];
  const int tid = threadIdx.x, lane = tid & 63, w = tid >> 6;
  const int n0 = blockIdx.x * 128;
  const int K = DI;
  f32x4 acc[5][2];
#pragma unroll
  for (int i = 0; i < 5; i++) { acc[i][0] = (f32x4){0,0,0,0}; acc[i][1] = (f32x4){0,0,0,0}; }

  const int rA = lane >> 2;
  const int c8 = (lane & 3) * 8;
  const int fr = lane & 15;
  const int fk = (lane >> 4) * 8;

  for (int k0 = 0; k0 < K; k0 += 32) {
#pragma unroll
    for (int j = 0; j < 2; j++) {
      int rr = (w * 2 + j) * 16;
      gld16(A + (size_t)(rr + rA) * K + k0 + c8, a_s + rr * 32);
      gld16(B + (size_t)(n0 + rr + rA) * K + k0 + c8, b_s + rr * 32);
    }
    __syncthreads();
    bf16x8 af[5], bf[2];
#pragma unroll
    for (int mi = 0; mi < 5; mi++)
      af[mi] = *(const bf16x8*)(a_s + (mi * 16 + fr) * 32 + fk);
#pragma unroll
    for (int ni = 0; ni < 2; ni++)
      bf[ni] = *(const bf16x8*)(b_s + (w * 32 + ni * 16 + fr) * 32 + fk);
#pragma unroll
    for (int mi = 0; mi < 5; mi++)
#pragma unroll
      for (int ni = 0; ni < 2; ni++)
        acc[mi][ni] = __builtin_amdgcn_mfma_f32_16x16x32_bf16(
            af[mi], bf[ni], acc[mi][ni], 0, 0, 0);
    __syncthreads();
  }

  const int rbase = (lane >> 4) * 4, cbase = lane & 15;
#pragma unroll
  for (int mi = 0; mi < 5; mi++)
#pragma unroll
    for (int ni = 0; ni < 2; ni++)
#pragma unroll
      for (int j = 0; j < 4; j++) {
        int m = mi * 16 + rbase + j;
        int n = n0 + w * 32 + ni * 16 + cbase;
        float v = acc[mi][ni][j];
        C[(size_t)n * SSMW + m] = v;
        if (m < 64) {
          u16 dv = (m < 48) ? f2b(v) : (m == 48 ? f2b(1.0f) : (u16)0);
          dtin[(size_t)n * 64 + m] = dv;
        }
      }
}

// ---------------- causal depthwise conv(4) + SiLU ----------------
__global__ __launch_bounds__(256) void conv_silu(const u16* __restrict__ proj,
                                                 const float* __restrict__ cw,
                                                 const float* __restrict__ cb,
                                                 u16* __restrict__ hidden) {
  __shared__ __align__(16) u16 in_s[64][96];
  __shared__ __align__(16) u16 o_s[64][64];
  const int t = threadIdx.x;
  const int d0 = blockIdx.x * 64, l0 = blockIdx.y * 64, bb = blockIdx.z;

  for (int c = t; c < 64 * 12; c += 256) {
    int r = c / 12, q = c % 12;
    int gl = l0 - 32 + q * 8;
    uint4 v;
    if (gl >= 0) v = *(const uint4*)(proj + ((size_t)bb * E2 + d0 + r) * LSEQ + gl);
    else         v = (uint4){0u, 0u, 0u, 0u};
    *(uint4*)(&in_s[r][q * 8]) = v;
  }
  __syncthreads();

  const int dd = t >> 2, ls = t & 3;
  const int d = d0 + dd;
  const float w0 = cw[d * 4 + 0], w1 = cw[d * 4 + 1], w2 = cw[d * 4 + 2], w3 = cw[d * 4 + 3];
  const float bias = cb[d];
#pragma unroll
  for (int i = 0; i < 16; i++) {
    int li = ls * 16 + i;
    int base = 32 + li - 3;
    float h = w0 * b2f(in_s[dd][base + 0]) + w1 * b2f(in_s[dd][base + 1]) +
              w2 * b2f(in_s[dd][base + 2]) + w3 * b2f(in_s[dd][base + 3]) + bias;
    o_s[li][dd] = f2b(silu_f(h));
  }
  __syncthreads();

  for (int c = t; c < 512; c += 256) {
    int r = c >> 3, q = c & 7;
    *(uint4*)(hidden + ((size_t)bb * LSEQ + l0 + r) * DI + d0 + q * 8) =
        *(const uint4*)(&o_s[r][q * 8]);
  }
}

// ================= chunked parallel suffix scan, dt fused via MFMA, f32 LDS =================
// dt tile [l0..l0+79][d0..d0+15] = softplus(dtin(K=64) . wdtp^T), stored f32.
// dt_f rows are 84 wide: the MFMA writes cols 0..79 (5 m-tiles x 16).

#define DT_TILE_MFMA(dtin, wdtp)                                                          \
  {                                                                                       \
    const u16* ar = dtin + ((size_t)bb * LSEQ + l0) * 64;                                 \
    bf16x8 wb0 = *(const bf16x8*)(wdtp + (size_t)(d0 + fr) * 64 + fk);                    \
    bf16x8 wb1 = *(const bf16x8*)(wdtp + (size_t)(d0 + fr) * 64 + 32 + fk);               \
    for (int mt = wv; mt < 5; mt += 4) {                                                  \
      bf16x8 a0 = *(const bf16x8*)(ar + (size_t)(mt * 16 + fr) * 64 + fk);                \
      bf16x8 a1 = *(const bf16x8*)(ar + (size_t)(mt * 16 + fr) * 64 + 32 + fk);           \
      f32x4 da = (f32x4){0.f, 0.f, 0.f, 0.f};                                             \
      da = __builtin_amdgcn_mfma_f32_16x16x32_bf16(a0, wb0, da, 0, 0, 0);                 \
      da = __builtin_amdgcn_mfma_f32_16x16x32_bf16(a1, wb1, da, 0, 0, 0);                 \
      _Pragma("unroll")                                                                   \
      for (int j = 0; j < 4; j++)                                                         \
        dt_f[cbase][mt * 16 + rbase + j] = softplus_f(da[j]);                             \
    }                                                                                     \
  }

// Phase A: per-chunk local summary -> gsum (g_local at l0), sdt (sum dt over (l0,l1])
__global__ __launch_bounds__(256) void scan_sum(const u16* __restrict__ dtin,
                                                const u16* __restrict__ wdtp,
                                                const u16* __restrict__ hidden,
                                                const float* __restrict__ ssm,
                                                const float* __restrict__ A_log,
                                                float* __restrict__ gsum,
                                                float* __restrict__ sdt) {
  __shared__ __align__(16) float dt_f[16][84];
  __shared__ __align__(16) float hid_f[16][68];
  __shared__ __align__(16) float B_t[16][68];
  const int t = threadIdx.x;
  const int d0 = blockIdx.x * 16, c = blockIdx.y, bb = blockIdx.z;
  const int dl = t >> 4, n = t & 15;
  const int d = d0 + dl;
  const int l0 = c * CP;
  const int lane = t & 63, wv = t >> 6;
  const int fr = lane & 15, fk = (lane >> 4) * 8;
  const int rbase = (lane >> 4) * 4, cbase = lane & 15;
  {
    int r = t >> 2, q = t & 3;
    size_t lbrow = (size_t)bb * LSEQ + l0 + r;
    uint2 hv = *(const uint2*)(hidden + lbrow * DI + d0 + q * 4);
    float4 bv = *(const float4*)(ssm + lbrow * SSMW + 48 + q * 4);
    hid_f[q * 4 + 0][r] = b2f((u16)hv.x); hid_f[q * 4 + 1][r] = b2f((u16)(hv.x >> 16));
    hid_f[q * 4 + 2][r] = b2f((u16)hv.y); hid_f[q * 4 + 3][r] = b2f((u16)(hv.y >> 16));
    B_t[q * 4 + 0][r] = bv.x; B_t[q * 4 + 1][r] = bv.y;
    B_t[q * 4 + 2][r] = bv.z; B_t[q * 4 + 3][r] = bv.w;
  }
  DT_TILE_MFMA(dtin, wdtp)
  const float An2 = -__expf(A_log[d * 16 + n]) * LOG2E;
  __syncthreads();
  float dt_prev = (c == NC - 1) ? 0.f : dt_f[dl][64];
  float g = 0.f, sumdt = 0.f;
#define STEPS(dtv_, hv_, Bv_) {            \
    float dtv = dtv_;                      \
    float dA = fexp2(An2 * dt_prev);       \
    g = dtv * (Bv_) * (hv_) + dA * g;      \
    sumdt += dt_prev;                      \
    dt_prev = dtv; }
#pragma unroll
  for (int s = 7; s >= 0; --s) {
    f32x4 t0 = *(const f32x4*)(&dt_f[dl][s * 8]);
    f32x4 t1 = *(const f32x4*)(&dt_f[dl][s * 8 + 4]);
    f32x4 h0 = *(const f32x4*)(&hid_f[dl][s * 8]);
    f32x4 h1 = *(const f32x4*)(&hid_f[dl][s * 8 + 4]);
    f32x4 b0 = *(const f32x4*)(&B_t[n][s * 8]);
    f32x4 b1 = *(const f32x4*)(&B_t[n][s * 8 + 4]);
    STEPS(t1[3], h1[3], b1[3]);
    STEPS(t1[2], h1[2], b1[2]);
    STEPS(t1[1], h1[1], b1[1]);
    STEPS(t1[0], h1[0], b1[0]);
    STEPS(t0[3], h0[3], b0[3]);
    STEPS(t0[2], h0[2], b0[2]);
    STEPS(t0[1], h0[1], b0[1]);
    STEPS(t0[0], h0[0], b0[0]);
  }
#undef STEPS
  size_t idx = (((size_t)bb * NC + c) * DI + d) * 16 + n;
  gsum[idx] = g;
  sdt[idx]  = sumdt;
}

// Phase B: serial combine over 32 chunk summaries -> carry[c]
__global__ __launch_bounds__(256) void scan_carry(const float* __restrict__ gsum,
                                                  const float* __restrict__ sdt,
                                                  const float* __restrict__ A_log,
                                                  float* __restrict__ carry) {
  const int t = blockIdx.x * 256 + threadIdx.x;
  const int bb = blockIdx.y;
  const int d = t >> 4, n = t & 15;
  const float An2 = -__expf(A_log[d * 16 + n]) * LOG2E;
  float cg = 0.f;
  carry[(((size_t)bb * NC + NC - 1) * DI + d) * 16 + n] = 0.f;
  for (int c = NC - 2; c >= 0; --c) {
    size_t up = (((size_t)bb * NC + (c + 1)) * DI + d) * 16 + n;
    cg = gsum[up] + fexp2(An2 * sdt[up]) * cg;
    carry[(((size_t)bb * NC + c) * DI + d) * 16 + n] = cg;
  }
}

// Phase C: re-run local scan seeded with carry; fuse C-proj, D, gating -> y
__global__ __launch_bounds__(256) void scan_apply(const u16* __restrict__ proj,
                                                  const u16* __restrict__ hidden,
                                                  const u16* __restrict__ dtin,
                                                  const u16* __restrict__ wdtp,
                                                  const float* __restrict__ ssm,
                                                  const float* __restrict__ A_log,
                                                  const float* __restrict__ Dp,
                                                  const float* __restrict__ carry,
                                                  u16* __restrict__ y) {
  __shared__ __align__(16) float dt_f[16][84];
  __shared__ __align__(16) float hid_f[16][68];
  __shared__ __align__(16) float B_t[16][68];
  __shared__ __align__(16) float C_t[16][68];
  __shared__ __align__(16) u16 gate_t[16][80];
  __shared__ __align__(16) u16 y_s[64][16];
  const int t = threadIdx.x;
  const int d0 = blockIdx.x * 16, c = blockIdx.y, bb = blockIdx.z;
  const int dl = t >> 4, n = t & 15;
  const int d = d0 + dl;
  const int l0 = c * CP;
  const int lane = t & 63, wv = t >> 6;
  const int fr = lane & 15, fk = (lane >> 4) * 8;
  const int rbase = (lane >> 4) * 4, cbase = lane & 15;
  {
    int r = t >> 2, q = t & 3;
    size_t lbrow = (size_t)bb * LSEQ + l0 + r;
    uint2 hv = *(const uint2*)(hidden + lbrow * DI + d0 + q * 4);
    float4 bv = *(const float4*)(ssm + lbrow * SSMW + 48 + q * 4);
    float4 cv = *(const float4*)(ssm + lbrow * SSMW + 64 + q * 4);
    hid_f[q * 4 + 0][r] = b2f((u16)hv.x); hid_f[q * 4 + 1][r] = b2f((u16)(hv.x >> 16));
    hid_f[q * 4 + 2][r] = b2f((u16)hv.y); hid_f[q * 4 + 3][r] = b2f((u16)(hv.y >> 16));
    B_t[q * 4 + 0][r] = bv.x; B_t[q * 4 + 1][r] = bv.y;
    B_t[q * 4 + 2][r] = bv.z; B_t[q * 4 + 3][r] = bv.w;
    C_t[q * 4 + 0][r] = cv.x; C_t[q * 4 + 1][r] = cv.y;
    C_t[q * 4 + 2][r] = cv.z; C_t[q * 4 + 3][r] = cv.w;
  }
  {
    int r = t >> 4, q = t & 15;
    *(uint2*)(&gate_t[r][q * 4]) =
        *(const uint2*)(proj + ((size_t)bb * E2 + DI + d0 + r) * LSEQ + l0 + q * 4);
  }
  DT_TILE_MFMA(dtin, wdtp)
  const float An2 = -__expf(A_log[d * 16 + n]) * LOG2E;
  const float Dd = Dp[d];
  float g = carry[(((size_t)bb * NC + c) * DI + d) * 16 + n];
  __syncthreads();
  float dt_prev = (c == NC - 1) ? 0.f : dt_f[dl][64];

  // Named capture registers (rule #20: array-indexed pcap went to scratch — r12 post-mortem).
#define STEP1(IDX, dtv_, hv_, Bv_, Cv_, PC) {              \
    float dtv = dtv_;                                      \
    float dA = fexp2(An2 * dt_prev);                       \
    g = dtv * (Bv_) * (hv_) + dA * g;                      \
    float p = g * (Cv_);                                   \
    ROWSUM16(p);                                           \
    if (n == ((IDX) & 15)) PC = p;                         \
    dt_prev = dtv; }
#define STEP8(S, PC) {                                          \
    f32x4 t0 = *(const f32x4*)(&dt_f[dl][(S) * 8]);             \
    f32x4 t1 = *(const f32x4*)(&dt_f[dl][(S) * 8 + 4]);         \
    f32x4 h0 = *(const f32x4*)(&hid_f[dl][(S) * 8]);            \
    f32x4 h1 = *(const f32x4*)(&hid_f[dl][(S) * 8 + 4]);        \
    f32x4 b0 = *(const f32x4*)(&B_t[n][(S) * 8]);               \
    f32x4 b1 = *(const f32x4*)(&B_t[n][(S) * 8 + 4]);           \
    f32x4 c0 = *(const f32x4*)(&C_t[n][(S) * 8]);               \
    f32x4 c1 = *(const f32x4*)(&C_t[n][(S) * 8 + 4]);           \
    STEP1((S) * 8 + 7, t1[3], h1[3], b1[3], c1[3], PC);         \
    STEP1((S) * 8 + 6, t1[2], h1[2], b1[2], c1[2], PC);         \
    STEP1((S) * 8 + 5, t1[1], h1[1], b1[1], c1[1], PC);         \
    STEP1((S) * 8 + 4, t1[0], h1[0], b1[0], c1[0], PC);         \
    STEP1((S) * 8 + 3, t0[3], h0[3], b0[3], c0[3], PC);         \
    STEP1((S) * 8 + 2, t0[2], h0[2], b0[2], c0[2], PC);         \
    STEP1((S) * 8 + 1, t0[1], h0[1], b0[1], c0[1], PC);         \
    STEP1((S) * 8 + 0, t0[0], h0[0], b0[0], c0[0], PC);         \
  }
  // slot = IDX>>4 is constant over each pair of STEP8 groups; descending l order.
  float p3 = 0.f, p2 = 0.f, p1 = 0.f, p0 = 0.f;
  STEP8(7, p3) STEP8(6, p3)
  STEP8(5, p2) STEP8(4, p2)
  STEP8(3, p1) STEP8(2, p1)
  STEP8(1, p0) STEP8(0, p0)
#undef STEP8
#undef STEP1

#define EPI(J, P) {                                        \
    float hval = hid_f[dl][n + 16 * (J)];                  \
    float gv = b2f(gate_t[dl][n + 16 * (J)]);              \
    float yv = (1.3f * (P) + hval * Dd) * silu_f(gv);      \
    y_s[n + 16 * (J)][dl] = f2b(yv); }
  EPI(0, p0) EPI(1, p1) EPI(2, p2) EPI(3, p3)
#undef EPI
  __syncthreads();
  {
    int r = t >> 2, q = t & 3;
    *(uint2*)(y + ((size_t)bb * LSEQ + l0 + r) * DI + d0 + q * 4) =
        *(const uint2*)(&y_s[r][q * 4]);
  }
}

// ---------------- host ----------------
extern "C" void kernel_launch(void* const* d_in, const int* in_sizes, int n_in,
                              void* d_out, int out_size, void* d_ws, size_t ws_size,
                              hipStream_t stream) {
  const float* x_in   = (const float*)d_in[0];
  const float* w_in   = (const float*)d_in[1];
  const float* conv_w = (const float*)d_in[2];
  const float* conv_b = (const float*)d_in[3];
  const float* w_x    = (const float*)d_in[4];
  const float* w_dt   = (const float*)d_in[5];
  const float* b_dt   = (const float*)d_in[6];
  const float* A_log  = (const float*)d_in[7];
  const float* Dp     = (const float*)d_in[8];
  const float* w_out  = (const float*)d_in[9];
  float* outp = (float*)d_out;

  size_t off = 0;
  auto carve = [&](size_t bytes) {
    void* p = (char*)d_ws + off;
    off += (bytes + 255) & ~(size_t)255;
    return p;
  };
  u16*   in_b   = (u16*)  carve((size_t)NLB * DM * 2);
  u16*   win_b  = (u16*)  carve((size_t)E2 * DM * 2);
  u16*   wout_b = (u16*)  carve((size_t)DM * DI * 2);
  u16*   wx_b   = (u16*)  carve((size_t)SSMW * DI * 2);
  u16*   wdtp_b = (u16*)  carve((size_t)DI * 64 * 2);
  u16*   proj_b = (u16*)  carve((size_t)NB * E2 * LSEQ * 2);
  u16*   hid_b  = (u16*)  carve((size_t)NLB * DI * 2);
  float* ssm_b  = (float*)carve((size_t)NLB * SSMW * 4);
  u16*   dtin_b = (u16*)  carve((size_t)(NLB + 64) * 64 * 2);  // +64 rows OOB-read slack
  u16*   y_b    = (u16*)  carve((size_t)NLB * DI * 2);
  float* gsum_b = (float*)carve((size_t)NB * NC * DI * 16 * 4);
  float* sdt_b  = (float*)carve((size_t)NB * NC * DI * 16 * 4);
  float* car_b  = (float*)carve((size_t)NB * NC * DI * 16 * 4);

  const int ncast = NLB * DM + E2 * DM + DM * DI + SSMW * DI + DI * 64;
  castall<<<(ncast + 1023) / 1024, 256, 0, stream>>>(
      x_in, w_in, w_out, w_x, w_dt, b_dt, in_b, win_b, wout_b, wx_b, wdtp_b);

  gemm_bt<0><<<dim3(E2 / 128, NLB / 128), 256, 0, stream>>>(
      win_b, in_b, proj_b, E2, NLB, DM);
  conv_silu<<<dim3(DI / 64, LSEQ / 64, NB), 256, 0, stream>>>(
      proj_b, conv_w, conv_b, hid_b);
  gemm_xproj<<<NLB / 128, 256, 0, stream>>>(wx_b, hid_b, ssm_b, dtin_b);

  scan_sum<<<dim3(DI / 16, NC, NB), 256, 0, stream>>>(
      dtin_b, wdtp_b, hid_b, ssm_b, A_log, gsum_b, sdt_b);
  scan_carry<<<dim3(DI * 16 / 256, NB), 256, 0, stream>>>(
      gsum_b, sdt_b, A_log, car_b);
  scan_apply<<<dim3(DI / 16, NC, NB), 256, 0, stream>>>(
      proj_b, hid_b, dtin_b, wdtp_b, ssm_b, A_log, Dp, car_b, y_b);

  gemm_bt<1><<<dim3(NLB / 128, DM / 128), 256, 0, stream>>>(
      y_b, wout_b, outp, NLB, DM, DI);
}